// Round 1
// baseline (6283.848 us; speedup 1.0000x reference)
//
#include <hip/hip_runtime.h>
#include <math.h>

// AttenSeq2Seq on a sparse voxel grid. G=32, N=100000, C=96, all fp32.
// Pipeline: prep(flat,cnt) -> [scatter -> conv3d -> devox(+lin,+fusions)] x5 stages.
// Conv weights pre-transposed to [tap][ci][co]; lin weights to [ci][co].
// Submanifold occ-mask folded into the devox gate (w *= valid && cnt>0).
// Workspace ~134 MB.

#define GD 32
#define NV (GD*GD*GD)   // 32768 voxels
#define CH 96

// ---------------- small kernels ----------------

__global__ void k_prep(const float* __restrict__ coords, int* __restrict__ flat,
                       unsigned* __restrict__ cnt, int n) {
  int i = blockIdx.x * 256 + threadIdx.x;
  if (i >= n) return;
  float x = coords[3*i], y = coords[3*i+1], z = coords[3*i+2];
  int ix = (int)floorf(x); ix = ix < 0 ? 0 : (ix > 31 ? 31 : ix);
  int iy = (int)floorf(y); iy = iy < 0 ? 0 : (iy > 31 ? 31 : iy);
  int iz = (int)floorf(z); iz = iz < 0 ? 0 : (iz > 31 ? 31 : iz);
  int f = (ix << 10) + (iy << 5) + iz;
  flat[i] = f;
  atomicAdd(&cnt[f], 1u);
}

__global__ void k_inv(const unsigned* __restrict__ cnt, float* __restrict__ inv) {
  int v = blockIdx.x * 256 + threadIdx.x;
  if (v >= NV) return;
  unsigned c = cnt[v];
  inv[v] = c ? 1.0f / (float)c : 0.0f;
}

// conv weight (Co,Ci,27) -> (27,Ci,Co)
__global__ void k_tconv(const float* __restrict__ w, float* __restrict__ wt, int Co, int Ci) {
  int e = blockIdx.x * 256 + threadIdx.x;
  int total = Co * Ci * 27;
  if (e >= total) return;
  int co = e % Co; int r = e / Co; int ci = r % Ci; int tap = r / Ci;
  wt[e] = w[(co * Ci + ci) * 27 + tap];
}

// lin weight (Co,Ci) -> (Ci,Co)
__global__ void k_tlin(const float* __restrict__ w, float* __restrict__ wt, int Co, int Ci) {
  int e = blockIdx.x * 256 + threadIdx.x;
  if (e >= Co * Ci) return;
  int co = e % Co; int ci = e / Co;
  wt[e] = w[co * Ci + ci];
}

// scatter-mean: grid[flat[p]*96+ch] += feats[p,ch] * inv_cnt[flat[p]] * (scale?scale[p]:1)
__global__ void k_scatter(const float* __restrict__ feats, const float* __restrict__ scale,
                          const int* __restrict__ flat, const float* __restrict__ inv,
                          float* __restrict__ grid, int n) {
  int e = blockIdx.x * 256 + threadIdx.x;
  if (e >= n * CH) return;
  int p = e / CH, ch = e - p * CH;
  int f = flat[p];
  float v = feats[e] * inv[f];
  if (scale) v *= scale[p];
  atomicAdd(&grid[f * CH + ch], v);
}

// ---------------- 3x3x3 conv over the 32^3 grid ----------------
// One workgroup per (x,y) column; 128 threads; thread tile 4z x 6co.
// LDS: 9 neighbor columns x 34 z x 32 ch (chunked over Cin), ch padded to 33.
// CINB = number of 96-ch input blocks (1 or 2; block 2 comes from gB).
template<int CINB>
__global__ __launch_bounds__(128) void k_conv3d(
    const float* __restrict__ gA, const float* __restrict__ gB,
    const float* __restrict__ wt, float* __restrict__ out) {
  constexpr int CIN = CINB * CH;
  __shared__ float lg[9 * 34 * 33];
  __shared__ float lw[32 * CH];
  int bx = blockIdx.x >> 5, by = blockIdx.x & 31;
  int tid = threadIdx.x;
  int z0 = (tid >> 4) * 4;
  int co0 = (tid & 15) * 6;
  float acc[4][6];
#pragma unroll
  for (int a = 0; a < 4; ++a)
#pragma unroll
    for (int b = 0; b < 6; ++b) acc[a][b] = 0.f;

  for (int chunk = 0; chunk < CINB * 3; ++chunk) {
    const float* g = (CINB == 2 && chunk >= 3) ? gB : gA;
    int c0 = (chunk >= 3 ? chunk - 3 : chunk) * 32;
    __syncthreads();  // protect lg from previous chunk's readers
    for (int e = tid; e < 9 * 34 * 32; e += 128) {
      int col = e / 1088; int rem = e - col * 1088;
      int zz = rem >> 5; int c = rem & 31;
      int x = bx + col / 3 - 1;
      int y = by + (col - (col / 3) * 3) - 1;
      int zv = zz - 1;
      float val = 0.f;
      if ((unsigned)x < 32u && (unsigned)y < 32u && (unsigned)zv < 32u)
        val = g[((x << 10) + (y << 5) + zv) * CH + c0 + c];
      lg[(col * 34 + zz) * 33 + c] = val;
    }
    for (int tap = 0; tap < 27; ++tap) {
      __syncthreads();  // lg ready (first tap) / protect lw (later taps)
      const float* wsrc = wt + (tap * CIN + chunk * 32) * CH;
      for (int e = tid; e < 32 * CH; e += 128) lw[e] = wsrc[e];
      __syncthreads();
      int cc = tap / 3, dz = tap - cc * 3;  // cc = (kx*3+ky) neighbor column, dz = kz
      const float* lgp = &lg[(cc * 34 + z0 + dz) * 33];
#pragma unroll 4
      for (int c = 0; c < 32; ++c) {
        float gg[4];
        gg[0] = lgp[c];
        gg[1] = lgp[c + 33];
        gg[2] = lgp[c + 66];
        gg[3] = lgp[c + 99];
        const float2* lwp = reinterpret_cast<const float2*>(&lw[c * CH + co0]);
        float2 wa = lwp[0], wb = lwp[1], wc = lwp[2];
        float ww[6] = {wa.x, wa.y, wb.x, wb.y, wc.x, wc.y};
#pragma unroll
        for (int zt = 0; zt < 4; ++zt)
#pragma unroll
          for (int ct = 0; ct < 6; ++ct) acc[zt][ct] += gg[zt] * ww[ct];
      }
    }
  }
  int vbase = ((bx << 10) + (by << 5) + z0) * CH + co0;
#pragma unroll
  for (int zt = 0; zt < 4; ++zt)
#pragma unroll
    for (int ct = 0; ct < 6; ++ct) out[vbase + zt * CH + ct] = acc[zt][ct];
}

// Cout=1 conv (the 'v' attention head). 128 thr: z = tid&31, 4 ci-partials reduced in LDS.
__global__ __launch_bounds__(128) void k_conv3d_v(
    const float* __restrict__ g, const float* __restrict__ wt, float* __restrict__ out) {
  __shared__ float lg[9 * 34 * 33];
  __shared__ float red[128];
  int bx = blockIdx.x >> 5, by = blockIdx.x & 31;
  int tid = threadIdx.x;
  int z = tid & 31, part = tid >> 5;
  float acc = 0.f;
  for (int chunk = 0; chunk < 3; ++chunk) {
    int c0 = chunk * 32;
    __syncthreads();
    for (int e = tid; e < 9 * 34 * 32; e += 128) {
      int col = e / 1088; int rem = e - col * 1088;
      int zz = rem >> 5; int c = rem & 31;
      int x = bx + col / 3 - 1;
      int y = by + (col - (col / 3) * 3) - 1;
      int zv = zz - 1;
      float val = 0.f;
      if ((unsigned)x < 32u && (unsigned)y < 32u && (unsigned)zv < 32u)
        val = g[((x << 10) + (y << 5) + zv) * CH + c0 + c];
      lg[(col * 34 + zz) * 33 + c] = val;
    }
    __syncthreads();
    for (int tap = 0; tap < 27; ++tap) {
      int cc = tap / 3, dz = tap - cc * 3;
      const float* lgp = &lg[(cc * 34 + z + dz) * 33 + part * 8];
      const float* wp = wt + tap * CH + c0 + part * 8;
#pragma unroll
      for (int c = 0; c < 8; ++c) acc += lgp[c] * wp[c];
    }
  }
  red[tid] = acc;
  __syncthreads();
  if (part == 0)
    out[(bx << 10) + (by << 5) + z] = red[z] + red[z + 32] + red[z + 64] + red[z + 96];
}

// ---------------- trilinear devoxelize (+linear, + fusions) ----------------

__device__ __forceinline__ void corner_one(
    const float* __restrict__ coords, const unsigned* __restrict__ cnt,
    int p, int k, int& flc, float& w) {
  float cx = coords[3*p], cy = coords[3*p+1], cz = coords[3*p+2];
  float bx = floorf(cx), by = floorf(cy), bz = floorf(cz);
  float fx = cx - bx, fy = cy - by, fz = cz - bz;
  int dx = (k >> 2) & 1, dy = (k >> 1) & 1, dzz = k & 1;
  int ix = (int)bx + dx, iy = (int)by + dy, iz = (int)bz + dzz;
  bool valid = ((unsigned)ix < 32u) && ((unsigned)iy < 32u) && ((unsigned)iz < 32u);
  int xc = min(max(ix, 0), 31), yc = min(max(iy, 0), 31), zc = min(max(iz, 0), 31);
  flc = (xc << 10) + (yc << 5) + zc;
  float wx = dx ? fx : 1.f - fx;
  float wy = dy ? fy : 1.f - fy;
  float wz = dzz ? fz : 1.f - fz;
  w = (valid && cnt[flc] > 0u) ? wx * wy * wz : 0.f;
}

// 8 points/block, 24 co-threads x 4 co each. dst = devox(outv) + feats@lwT + lb
__global__ __launch_bounds__(192) void k_devox_lin(
    const float* __restrict__ outv, const float* __restrict__ feats,
    const float* __restrict__ lwT, const float* __restrict__ lb,
    const float* __restrict__ coords, const unsigned* __restrict__ cnt,
    float* __restrict__ dst, int n) {
  __shared__ int lflc[8][8];
  __shared__ float lcw[8][8];
  __shared__ float lf[8][CH];
  int tid = threadIdx.x, p0 = blockIdx.x * 8;
  if (tid < 64) {
    int j = tid >> 3, k = tid & 7, p = p0 + j;
    int f = 0; float w = 0.f;
    if (p < n) corner_one(coords, cnt, p, k, f, w);
    lflc[j][k] = f; lcw[j][k] = w;
  }
  for (int e = tid; e < 8 * CH; e += 192) {
    int j = e / CH, c = e - j * CH; int p = p0 + j;
    lf[j][c] = (p < n) ? feats[p * CH + c] : 0.f;
  }
  __syncthreads();
  int j = tid / 24, lc = tid - j * 24, co0 = lc * 4;
  int p = p0 + j;
  float4 a = *reinterpret_cast<const float4*>(lb + co0);
#pragma unroll 4
  for (int ci = 0; ci < CH; ++ci) {
    float f = lf[j][ci];
    float4 w = *reinterpret_cast<const float4*>(lwT + ci * CH + co0);
    a.x += f * w.x; a.y += f * w.y; a.z += f * w.z; a.w += f * w.w;
  }
#pragma unroll
  for (int k = 0; k < 8; ++k) {
    float w = lcw[j][k];
    float4 o = *reinterpret_cast<const float4*>(outv + lflc[j][k] * CH + co0);
    a.x += w * o.x; a.y += w * o.y; a.z += w * o.z; a.w += w * o.w;
  }
  if (p < n) *reinterpret_cast<float4*>(dst + p * CH + co0) = a;
}

// energy stage, fused: e = tanh(devox(outvATT) + h@lwT[0:96] + q@lwT[96:192] + lb);
// scatter e into voxE; attn[p] = sum_co e*v_lw[co] (v-linear partial).
__global__ __launch_bounds__(192) void k_devox_energy(
    const float* __restrict__ outv, const float* __restrict__ h, const float* __restrict__ q,
    const float* __restrict__ lwT, const float* __restrict__ lb, const float* __restrict__ vlw,
    const float* __restrict__ coords, const unsigned* __restrict__ cnt,
    const int* __restrict__ flat, const float* __restrict__ inv,
    float* __restrict__ voxE, float* __restrict__ attn, int n) {
  __shared__ int lflc[8][8];
  __shared__ float lcw[8][8];
  __shared__ float lh[8][CH], lq[8][CH];
  __shared__ float red[192];
  int tid = threadIdx.x, p0 = blockIdx.x * 8;
  if (tid < 64) {
    int j = tid >> 3, k = tid & 7, p = p0 + j;
    int f = 0; float w = 0.f;
    if (p < n) corner_one(coords, cnt, p, k, f, w);
    lflc[j][k] = f; lcw[j][k] = w;
  }
  for (int e = tid; e < 8 * CH; e += 192) {
    int j = e / CH, c = e - j * CH; int p = p0 + j;
    lh[j][c] = (p < n) ? h[p * CH + c] : 0.f;
    lq[j][c] = (p < n) ? q[p * CH + c] : 0.f;
  }
  __syncthreads();
  int j = tid / 24, lc = tid - j * 24, co0 = lc * 4;
  int p = p0 + j;
  float4 a = *reinterpret_cast<const float4*>(lb + co0);
#pragma unroll 4
  for (int ci = 0; ci < CH; ++ci) {
    float f = lh[j][ci];
    float4 w = *reinterpret_cast<const float4*>(lwT + ci * CH + co0);
    a.x += f * w.x; a.y += f * w.y; a.z += f * w.z; a.w += f * w.w;
  }
#pragma unroll 4
  for (int ci = 0; ci < CH; ++ci) {
    float f = lq[j][ci];
    float4 w = *reinterpret_cast<const float4*>(lwT + (CH + ci) * CH + co0);
    a.x += f * w.x; a.y += f * w.y; a.z += f * w.z; a.w += f * w.w;
  }
#pragma unroll
  for (int k = 0; k < 8; ++k) {
    float w = lcw[j][k];
    float4 o = *reinterpret_cast<const float4*>(outv + lflc[j][k] * CH + co0);
    a.x += w * o.x; a.y += w * o.y; a.z += w * o.z; a.w += w * o.w;
  }
  float e0 = tanhf(a.x), e1 = tanhf(a.y), e2 = tanhf(a.z), e3 = tanhf(a.w);
  if (p < n) {
    int f = flat[p]; float iv = inv[f];
    float* vb = voxE + f * CH + co0;
    atomicAdd(vb + 0, e0 * iv); atomicAdd(vb + 1, e1 * iv);
    atomicAdd(vb + 2, e2 * iv); atomicAdd(vb + 3, e3 * iv);
  }
  float4 vw = *reinterpret_cast<const float4*>(vlw + co0);
  red[tid] = e0 * vw.x + e1 * vw.y + e2 * vw.z + e3 * vw.w;
  __syncthreads();
  if (lc == 0 && p < n) {
    float s = 0.f;
#pragma unroll
    for (int t = 0; t < 24; ++t) s += red[j * 24 + t];
    attn[p] = s;
  }
}

__global__ void k_attn_final(const float* __restrict__ outvV, const float* __restrict__ vlb,
                             const float* __restrict__ coords, const unsigned* __restrict__ cnt,
                             float* __restrict__ attn, int n) {
  int p = blockIdx.x * 256 + threadIdx.x;
  if (p >= n) return;
  float a = attn[p] + vlb[0];
#pragma unroll
  for (int k = 0; k < 8; ++k) {
    int f; float w;
    corner_one(coords, cnt, p, k, f, w);
    a += w * outvV[f];
  }
  attn[p] = a;
}

// final stage: out = tanh(devox(outvUPD) + q@lwT[0:96] + (attn*h)@lwT[96:192] + lb)
__global__ __launch_bounds__(192) void k_devox_final(
    const float* __restrict__ outv, const float* __restrict__ q, const float* __restrict__ h,
    const float* __restrict__ attn, const float* __restrict__ lwT, const float* __restrict__ lb,
    const float* __restrict__ coords, const unsigned* __restrict__ cnt,
    float* __restrict__ dst, int n) {
  __shared__ int lflc[8][8];
  __shared__ float lcw[8][8];
  __shared__ float lq[8][CH], lctx[8][CH];
  int tid = threadIdx.x, p0 = blockIdx.x * 8;
  if (tid < 64) {
    int j = tid >> 3, k = tid & 7, p = p0 + j;
    int f = 0; float w = 0.f;
    if (p < n) corner_one(coords, cnt, p, k, f, w);
    lflc[j][k] = f; lcw[j][k] = w;
  }
  for (int e = tid; e < 8 * CH; e += 192) {
    int j = e / CH, c = e - j * CH; int p = p0 + j;
    if (p < n) {
      float av = attn[p];
      lq[j][c] = q[p * CH + c];
      lctx[j][c] = av * h[p * CH + c];
    } else {
      lq[j][c] = 0.f; lctx[j][c] = 0.f;
    }
  }
  __syncthreads();
  int j = tid / 24, lc = tid - j * 24, co0 = lc * 4;
  int p = p0 + j;
  float4 a = *reinterpret_cast<const float4*>(lb + co0);
#pragma unroll 4
  for (int ci = 0; ci < CH; ++ci) {
    float f = lq[j][ci];
    float4 w = *reinterpret_cast<const float4*>(lwT + ci * CH + co0);
    a.x += f * w.x; a.y += f * w.y; a.z += f * w.z; a.w += f * w.w;
  }
#pragma unroll 4
  for (int ci = 0; ci < CH; ++ci) {
    float f = lctx[j][ci];
    float4 w = *reinterpret_cast<const float4*>(lwT + (CH + ci) * CH + co0);
    a.x += f * w.x; a.y += f * w.y; a.z += f * w.z; a.w += f * w.w;
  }
#pragma unroll
  for (int k = 0; k < 8; ++k) {
    float w = lcw[j][k];
    float4 o = *reinterpret_cast<const float4*>(outv + lflc[j][k] * CH + co0);
    a.x += w * o.x; a.y += w * o.y; a.z += w * o.z; a.w += w * o.w;
  }
  if (p < n) {
    float4 r;
    r.x = tanhf(a.x); r.y = tanhf(a.y); r.z = tanhf(a.z); r.w = tanhf(a.w);
    *reinterpret_cast<float4*>(dst + p * CH + co0) = r;
  }
}

// ---------------- launch ----------------

extern "C" void kernel_launch(void* const* d_in, const int* in_sizes, int n_in,
                              void* d_out, int out_size, void* d_ws, size_t ws_size,
                              hipStream_t stream) {
  const float* hidden   = (const float*)d_in[0];
  const float* query    = (const float*)d_in[1];
  const float* coords   = (const float*)d_in[2];
  const float* wq_conv  = (const float*)d_in[3];
  const float* wq_lw    = (const float*)d_in[4];
  const float* wq_lb    = (const float*)d_in[5];
  const float* wh_conv  = (const float*)d_in[6];
  const float* wh_lw    = (const float*)d_in[7];
  const float* wh_lb    = (const float*)d_in[8];
  const float* att_conv = (const float*)d_in[9];
  const float* att_lw   = (const float*)d_in[10];
  const float* att_lb   = (const float*)d_in[11];
  const float* v_conv   = (const float*)d_in[12];
  const float* v_lw     = (const float*)d_in[13];
  const float* v_lb     = (const float*)d_in[14];
  const float* upd_conv = (const float*)d_in[15];
  const float* upd_lw   = (const float*)d_in[16];
  const float* upd_lb   = (const float*)d_in[17];
  float* out = (float*)d_out;
  const int n = in_sizes[0] / CH;

  char* wsp = (char*)d_ws;
  auto alloc = [&](size_t bytes) {
    char* r = wsp;
    wsp += (bytes + 255) & ~(size_t)255;
    return r;
  };
  int*      flat = (int*)     alloc((size_t)n * 4);
  unsigned* cnt  = (unsigned*)alloc((size_t)NV * 4);
  float*    inv  = (float*)   alloc((size_t)NV * 4);
  float*    attn = (float*)   alloc((size_t)n * 4);
  float* wtq  = (float*)alloc((size_t)27 * 96 * 96 * 4);
  float* wth  = (float*)alloc((size_t)27 * 96 * 96 * 4);
  float* wta  = (float*)alloc((size_t)27 * 192 * 96 * 4);
  float* wtv  = (float*)alloc((size_t)27 * 96 * 4);
  float* wtu  = (float*)alloc((size_t)27 * 192 * 96 * 4);
  float* lwqT = (float*)alloc((size_t)96 * 96 * 4);
  float* lwhT = (float*)alloc((size_t)96 * 96 * 4);
  float* lwaT = (float*)alloc((size_t)192 * 96 * 4);
  float* lwuT = (float*)alloc((size_t)192 * 96 * 4);
  float* G1 = (float*)alloc((size_t)NV * CH * 4);
  float* G2 = (float*)alloc((size_t)NV * CH * 4);
  float* O1 = (float*)alloc((size_t)NV * CH * 4);
  float* O2 = (float*)alloc((size_t)NV * CH * 4);
  float* qv = (float*)alloc((size_t)n * CH * 4);
  float* hv = (float*)alloc((size_t)n * CH * 4);

  const size_t gbytes = (size_t)NV * CH * 4;
  const int nb  = (n + 255) / 256;
  const int nbs = (n * CH + 255) / 256;
  const int ndv = (n + 7) / 8;

  // prep: voxel ids, counts, inverse counts; weight transposes
  hipMemsetAsync(cnt, 0, (size_t)NV * 4, stream);
  k_prep<<<nb, 256, 0, stream>>>(coords, flat, cnt, n);
  k_inv<<<(NV + 255) / 256, 256, 0, stream>>>(cnt, inv);
  k_tconv<<<(27*96*96 + 255)/256, 256, 0, stream>>>(wq_conv, wtq, 96, 96);
  k_tconv<<<(27*96*96 + 255)/256, 256, 0, stream>>>(wh_conv, wth, 96, 96);
  k_tconv<<<(27*192*96 + 255)/256, 256, 0, stream>>>(att_conv, wta, 96, 192);
  k_tconv<<<(27*96 + 255)/256, 256, 0, stream>>>(v_conv, wtv, 1, 96);
  k_tconv<<<(27*192*96 + 255)/256, 256, 0, stream>>>(upd_conv, wtu, 96, 192);
  k_tlin<<<(96*96 + 255)/256, 256, 0, stream>>>(wq_lw, lwqT, 96, 96);
  k_tlin<<<(96*96 + 255)/256, 256, 0, stream>>>(wh_lw, lwhT, 96, 96);
  k_tlin<<<(192*96 + 255)/256, 256, 0, stream>>>(att_lw, lwaT, 96, 192);
  k_tlin<<<(192*96 + 255)/256, 256, 0, stream>>>(upd_lw, lwuT, 96, 192);

  // stage 1: q = sconv(query)
  hipMemsetAsync(G1, 0, gbytes, stream);
  k_scatter<<<nbs, 256, 0, stream>>>(query, nullptr, flat, inv, G1, n);
  k_conv3d<1><<<1024, 128, 0, stream>>>(G1, G1, wtq, O1);
  k_devox_lin<<<ndv, 192, 0, stream>>>(O1, query, lwqT, wq_lb, coords, cnt, qv, n);

  // stage 2: h = sconv(hidden)
  hipMemsetAsync(G2, 0, gbytes, stream);
  k_scatter<<<nbs, 256, 0, stream>>>(hidden, nullptr, flat, inv, G2, n);
  k_conv3d<1><<<1024, 128, 0, stream>>>(G2, G2, wth, O2);
  k_devox_lin<<<ndv, 192, 0, stream>>>(O2, hidden, lwhT, wh_lb, coords, cnt, hv, n);

  // stage 3: energy = tanh(sconv([h,q])) -> scattered into G1 (voxE) + v-linear partial in attn
  hipMemsetAsync(G1, 0, gbytes, stream);
  hipMemsetAsync(G2, 0, gbytes, stream);
  k_scatter<<<nbs, 256, 0, stream>>>(hv, nullptr, flat, inv, G1, n);
  k_scatter<<<nbs, 256, 0, stream>>>(qv, nullptr, flat, inv, G2, n);   // G2 = vox(q), reused in stage 5
  k_conv3d<2><<<1024, 128, 0, stream>>>(G1, G2, wta, O1);
  hipMemsetAsync(G1, 0, gbytes, stream);                               // G1 becomes voxE
  k_devox_energy<<<ndv, 192, 0, stream>>>(O1, hv, qv, lwaT, att_lb, v_lw,
                                          coords, cnt, flat, inv, G1, attn, n);

  // stage 4: attn = sconv(energy) with Cout=1
  k_conv3d_v<<<1024, 128, 0, stream>>>(G1, wtv, O2);
  k_attn_final<<<nb, 256, 0, stream>>>(O2, v_lb, coords, cnt, attn, n);

  // stage 5: out = tanh(sconv([q, attn*h]))
  hipMemsetAsync(G1, 0, gbytes, stream);                               // G1 becomes vox(attn*h)
  k_scatter<<<nbs, 256, 0, stream>>>(hv, attn, flat, inv, G1, n);
  k_conv3d<2><<<1024, 128, 0, stream>>>(G2, G1, wtu, O1);
  k_devox_final<<<ndv, 192, 0, stream>>>(O1, qv, hv, attn, lwuT, upd_lb,
                                         coords, cnt, out, n);
}

// Round 2
// 3304.135 us; speedup vs baseline: 1.9018x; 1.9018x over previous
//
#include <hip/hip_runtime.h>
#include <math.h>

// AttenSeq2Seq on a sparse voxel grid. G=32, N=100000, C=96, all fp32.
// R1: conv3d rewritten — no per-tap weight staging (weights read from L1/L2 in
// the FMA loop), 256 threads with split-ci halves + LDS reduce, [ci][col][z]
// LDS layout for aligned ds_read_b64, 14 barriers/block instead of 324.

#define GD 32
#define NV (GD*GD*GD)   // 32768 voxels
#define CH 96

// ---------------- small kernels ----------------

__global__ void k_prep(const float* __restrict__ coords, int* __restrict__ flat,
                       unsigned* __restrict__ cnt, int n) {
  int i = blockIdx.x * 256 + threadIdx.x;
  if (i >= n) return;
  float x = coords[3*i], y = coords[3*i+1], z = coords[3*i+2];
  int ix = (int)floorf(x); ix = ix < 0 ? 0 : (ix > 31 ? 31 : ix);
  int iy = (int)floorf(y); iy = iy < 0 ? 0 : (iy > 31 ? 31 : iy);
  int iz = (int)floorf(z); iz = iz < 0 ? 0 : (iz > 31 ? 31 : iz);
  int f = (ix << 10) + (iy << 5) + iz;
  flat[i] = f;
  atomicAdd(&cnt[f], 1u);
}

__global__ void k_inv(const unsigned* __restrict__ cnt, float* __restrict__ inv) {
  int v = blockIdx.x * 256 + threadIdx.x;
  if (v >= NV) return;
  unsigned c = cnt[v];
  inv[v] = c ? 1.0f / (float)c : 0.0f;
}

// conv weight (Co,Ci,27) -> (27,Ci,Co)
__global__ void k_tconv(const float* __restrict__ w, float* __restrict__ wt, int Co, int Ci) {
  int e = blockIdx.x * 256 + threadIdx.x;
  int total = Co * Ci * 27;
  if (e >= total) return;
  int co = e % Co; int r = e / Co; int ci = r % Ci; int tap = r / Ci;
  wt[e] = w[(co * Ci + ci) * 27 + tap];
}

// lin weight (Co,Ci) -> (Ci,Co)
__global__ void k_tlin(const float* __restrict__ w, float* __restrict__ wt, int Co, int Ci) {
  int e = blockIdx.x * 256 + threadIdx.x;
  if (e >= Co * Ci) return;
  int co = e % Co; int ci = e / Co;
  wt[e] = w[co * Ci + ci];
}

// scatter-mean: grid[flat[p]*96+ch] += feats[p,ch] * inv_cnt[flat[p]] * (scale?scale[p]:1)
__global__ void k_scatter(const float* __restrict__ feats, const float* __restrict__ scale,
                          const int* __restrict__ flat, const float* __restrict__ inv,
                          float* __restrict__ grid, int n) {
  int e = blockIdx.x * 256 + threadIdx.x;
  if (e >= n * CH) return;
  int p = e / CH, ch = e - p * CH;
  int f = flat[p];
  float v = feats[e] * inv[f];
  if (scale) v *= scale[p];
  atomicAdd(&grid[f * CH + ch], v);
}

// ---------------- 3x3x3 conv over the 32^3 grid ----------------
// One workgroup per (x,y) column; 256 threads (4 waves).
// Thread layout: cg = tid&15 (co-group, 6 co), zg = (tid>>4)&7 (z-group, 4 z),
// h = tid>>7 (ci half). Each half accumulates over half the ci; final LDS reduce.
// LDS tile: lg[ci=32][col=9][z=34] = 39168 B -> 4 blocks/CU.
// Weights read directly from global (L1-resident per-tap working set).
template<int CINB>
__global__ __launch_bounds__(256) void k_conv3d(
    const float* __restrict__ gA, const float* __restrict__ gB,
    const float* __restrict__ wt, float* __restrict__ out) {
  constexpr int CIN = CINB * CH;
  __shared__ float lg[32 * 9 * 34];
  int bx = blockIdx.x >> 5, by = blockIdx.x & 31;
  int tid = threadIdx.x;
  int cg = tid & 15;
  int zg = (tid >> 4) & 7;
  int h  = tid >> 7;
  int z0 = zg * 4;
  int co0 = cg * 6;
  float acc[4][6];
#pragma unroll
  for (int a = 0; a < 4; ++a)
#pragma unroll
    for (int b = 0; b < 6; ++b) acc[a][b] = 0.f;

  for (int chunk = 0; chunk < CINB * 3; ++chunk) {
    const float* g = (CINB == 2 && chunk >= 3) ? gB : gA;
    int c0 = (chunk >= 3 ? chunk - 3 : chunk) * 32;
    __syncthreads();  // protect lg from previous chunk's readers
    for (int e = tid; e < 9 * 34 * 32; e += 256) {
      int c = e & 31; int rem = e >> 5;        // rem = col*34 + z
      int col = rem / 34; int z = rem - col * 34;
      int x = bx + col / 3 - 1;
      int y = by + (col - (col / 3) * 3) - 1;
      int zv = z - 1;
      float val = 0.f;
      if ((unsigned)x < 32u && (unsigned)y < 32u && (unsigned)zv < 32u)
        val = g[((x << 10) + (y << 5) + zv) * CH + c0 + c];
      lg[(c * 9 + col) * 34 + z] = val;
    }
    __syncthreads();
    // compute: this half's ci within the chunk is [h*16, h*16+16)
    for (int col = 0; col < 9; ++col) {
      const float* wbase = wt + ((size_t)(col * 3) * CIN + chunk * 32 + h * 16) * CH + co0;
#pragma unroll 4
      for (int c = 0; c < 16; ++c) {
        const float* lp = &lg[((h * 16 + c) * 9 + col) * 34 + z0];
        float2 ga = *reinterpret_cast<const float2*>(lp);
        float2 gb = *reinterpret_cast<const float2*>(lp + 2);
        float2 gc = *reinterpret_cast<const float2*>(lp + 4);
        float gv[6] = {ga.x, ga.y, gb.x, gb.y, gc.x, gc.y};
        const float* wp = wbase + (size_t)c * CH;
#pragma unroll
        for (int dz = 0; dz < 3; ++dz) {
          const float* wq = wp + (size_t)dz * CIN * CH;
          float2 w0 = *reinterpret_cast<const float2*>(wq);
          float2 w1 = *reinterpret_cast<const float2*>(wq + 2);
          float2 w2 = *reinterpret_cast<const float2*>(wq + 4);
          float ww[6] = {w0.x, w0.y, w1.x, w1.y, w2.x, w2.y};
#pragma unroll
          for (int zt = 0; zt < 4; ++zt)
#pragma unroll
            for (int ct = 0; ct < 6; ++ct)
              acc[zt][ct] += gv[zt + dz] * ww[ct];
        }
      }
    }
  }
  // reduce the two ci-halves through LDS (stride 25 -> conflict-free)
  __syncthreads();
  float* red = lg;
  if (h == 1) {
    float* r = red + (tid - 128) * 25;
#pragma unroll
    for (int zt = 0; zt < 4; ++zt)
#pragma unroll
      for (int ct = 0; ct < 6; ++ct) r[zt * 6 + ct] = acc[zt][ct];
  }
  __syncthreads();
  if (h == 0) {
    const float* r = red + tid * 25;
    int vbase = ((bx << 10) + (by << 5) + z0) * CH + co0;
#pragma unroll
    for (int zt = 0; zt < 4; ++zt) {
      float2 o0, o1, o2;
      o0.x = acc[zt][0] + r[zt * 6 + 0]; o0.y = acc[zt][1] + r[zt * 6 + 1];
      o1.x = acc[zt][2] + r[zt * 6 + 2]; o1.y = acc[zt][3] + r[zt * 6 + 3];
      o2.x = acc[zt][4] + r[zt * 6 + 4]; o2.y = acc[zt][5] + r[zt * 6 + 5];
      float* op = out + vbase + zt * CH;
      *reinterpret_cast<float2*>(op)     = o0;
      *reinterpret_cast<float2*>(op + 2) = o1;
      *reinterpret_cast<float2*>(op + 4) = o2;
    }
  }
}

// Cout=1 conv (the 'v' attention head). 128 thr: z = tid&31, 4 ci-partials reduced in LDS.
__global__ __launch_bounds__(128) void k_conv3d_v(
    const float* __restrict__ g, const float* __restrict__ wt, float* __restrict__ out) {
  __shared__ float lg[9 * 34 * 33];
  __shared__ float red[128];
  int bx = blockIdx.x >> 5, by = blockIdx.x & 31;
  int tid = threadIdx.x;
  int z = tid & 31, part = tid >> 5;
  float acc = 0.f;
  for (int chunk = 0; chunk < 3; ++chunk) {
    int c0 = chunk * 32;
    __syncthreads();
    for (int e = tid; e < 9 * 34 * 32; e += 128) {
      int col = e / 1088; int rem = e - col * 1088;
      int zz = rem >> 5; int c = rem & 31;
      int x = bx + col / 3 - 1;
      int y = by + (col - (col / 3) * 3) - 1;
      int zv = zz - 1;
      float val = 0.f;
      if ((unsigned)x < 32u && (unsigned)y < 32u && (unsigned)zv < 32u)
        val = g[((x << 10) + (y << 5) + zv) * CH + c0 + c];
      lg[(col * 34 + zz) * 33 + c] = val;
    }
    __syncthreads();
    for (int tap = 0; tap < 27; ++tap) {
      int cc = tap / 3, dz = tap - cc * 3;
      const float* lgp = &lg[(cc * 34 + z + dz) * 33 + part * 8];
      const float* wp = wt + tap * CH + c0 + part * 8;
#pragma unroll
      for (int c = 0; c < 8; ++c) acc += lgp[c] * wp[c];
    }
  }
  red[tid] = acc;
  __syncthreads();
  if (part == 0)
    out[(bx << 10) + (by << 5) + z] = red[z] + red[z + 32] + red[z + 64] + red[z + 96];
}

// ---------------- trilinear devoxelize (+linear, + fusions) ----------------

__device__ __forceinline__ void corner_one(
    const float* __restrict__ coords, const unsigned* __restrict__ cnt,
    int p, int k, int& flc, float& w) {
  float cx = coords[3*p], cy = coords[3*p+1], cz = coords[3*p+2];
  float bx = floorf(cx), by = floorf(cy), bz = floorf(cz);
  float fx = cx - bx, fy = cy - by, fz = cz - bz;
  int dx = (k >> 2) & 1, dy = (k >> 1) & 1, dzz = k & 1;
  int ix = (int)bx + dx, iy = (int)by + dy, iz = (int)bz + dzz;
  bool valid = ((unsigned)ix < 32u) && ((unsigned)iy < 32u) && ((unsigned)iz < 32u);
  int xc = min(max(ix, 0), 31), yc = min(max(iy, 0), 31), zc = min(max(iz, 0), 31);
  flc = (xc << 10) + (yc << 5) + zc;
  float wx = dx ? fx : 1.f - fx;
  float wy = dy ? fy : 1.f - fy;
  float wz = dzz ? fz : 1.f - fz;
  w = (valid && cnt[flc] > 0u) ? wx * wy * wz : 0.f;
}

// 8 points/block, 24 co-threads x 4 co each. dst = devox(outv) + feats@lwT + lb
__global__ __launch_bounds__(192) void k_devox_lin(
    const float* __restrict__ outv, const float* __restrict__ feats,
    const float* __restrict__ lwT, const float* __restrict__ lb,
    const float* __restrict__ coords, const unsigned* __restrict__ cnt,
    float* __restrict__ dst, int n) {
  __shared__ int lflc[8][8];
  __shared__ float lcw[8][8];
  __shared__ float lf[8][CH];
  int tid = threadIdx.x, p0 = blockIdx.x * 8;
  if (tid < 64) {
    int j = tid >> 3, k = tid & 7, p = p0 + j;
    int f = 0; float w = 0.f;
    if (p < n) corner_one(coords, cnt, p, k, f, w);
    lflc[j][k] = f; lcw[j][k] = w;
  }
  for (int e = tid; e < 8 * CH; e += 192) {
    int j = e / CH, c = e - j * CH; int p = p0 + j;
    lf[j][c] = (p < n) ? feats[p * CH + c] : 0.f;
  }
  __syncthreads();
  int j = tid / 24, lc = tid - j * 24, co0 = lc * 4;
  int p = p0 + j;
  float4 a = *reinterpret_cast<const float4*>(lb + co0);
#pragma unroll 4
  for (int ci = 0; ci < CH; ++ci) {
    float f = lf[j][ci];
    float4 w = *reinterpret_cast<const float4*>(lwT + ci * CH + co0);
    a.x += f * w.x; a.y += f * w.y; a.z += f * w.z; a.w += f * w.w;
  }
#pragma unroll
  for (int k = 0; k < 8; ++k) {
    float w = lcw[j][k];
    float4 o = *reinterpret_cast<const float4*>(outv + lflc[j][k] * CH + co0);
    a.x += w * o.x; a.y += w * o.y; a.z += w * o.z; a.w += w * o.w;
  }
  if (p < n) *reinterpret_cast<float4*>(dst + p * CH + co0) = a;
}

// energy stage, fused: e = tanh(devox(outvATT) + h@lwT[0:96] + q@lwT[96:192] + lb);
// scatter e into voxE; attn[p] = sum_co e*v_lw[co] (v-linear partial).
__global__ __launch_bounds__(192) void k_devox_energy(
    const float* __restrict__ outv, const float* __restrict__ h, const float* __restrict__ q,
    const float* __restrict__ lwT, const float* __restrict__ lb, const float* __restrict__ vlw,
    const float* __restrict__ coords, const unsigned* __restrict__ cnt,
    const int* __restrict__ flat, const float* __restrict__ inv,
    float* __restrict__ voxE, float* __restrict__ attn, int n) {
  __shared__ int lflc[8][8];
  __shared__ float lcw[8][8];
  __shared__ float lh[8][CH], lq[8][CH];
  __shared__ float red[192];
  int tid = threadIdx.x, p0 = blockIdx.x * 8;
  if (tid < 64) {
    int j = tid >> 3, k = tid & 7, p = p0 + j;
    int f = 0; float w = 0.f;
    if (p < n) corner_one(coords, cnt, p, k, f, w);
    lflc[j][k] = f; lcw[j][k] = w;
  }
  for (int e = tid; e < 8 * CH; e += 192) {
    int j = e / CH, c = e - j * CH; int p = p0 + j;
    lh[j][c] = (p < n) ? h[p * CH + c] : 0.f;
    lq[j][c] = (p < n) ? q[p * CH + c] : 0.f;
  }
  __syncthreads();
  int j = tid / 24, lc = tid - j * 24, co0 = lc * 4;
  int p = p0 + j;
  float4 a = *reinterpret_cast<const float4*>(lb + co0);
#pragma unroll 4
  for (int ci = 0; ci < CH; ++ci) {
    float f = lh[j][ci];
    float4 w = *reinterpret_cast<const float4*>(lwT + ci * CH + co0);
    a.x += f * w.x; a.y += f * w.y; a.z += f * w.z; a.w += f * w.w;
  }
#pragma unroll 4
  for (int ci = 0; ci < CH; ++ci) {
    float f = lq[j][ci];
    float4 w = *reinterpret_cast<const float4*>(lwT + (CH + ci) * CH + co0);
    a.x += f * w.x; a.y += f * w.y; a.z += f * w.z; a.w += f * w.w;
  }
#pragma unroll
  for (int k = 0; k < 8; ++k) {
    float w = lcw[j][k];
    float4 o = *reinterpret_cast<const float4*>(outv + lflc[j][k] * CH + co0);
    a.x += w * o.x; a.y += w * o.y; a.z += w * o.z; a.w += w * o.w;
  }
  float e0 = tanhf(a.x), e1 = tanhf(a.y), e2 = tanhf(a.z), e3 = tanhf(a.w);
  if (p < n) {
    int f = flat[p]; float iv = inv[f];
    float* vb = voxE + f * CH + co0;
    atomicAdd(vb + 0, e0 * iv); atomicAdd(vb + 1, e1 * iv);
    atomicAdd(vb + 2, e2 * iv); atomicAdd(vb + 3, e3 * iv);
  }
  float4 vw = *reinterpret_cast<const float4*>(vlw + co0);
  red[tid] = e0 * vw.x + e1 * vw.y + e2 * vw.z + e3 * vw.w;
  __syncthreads();
  if (lc == 0 && p < n) {
    float s = 0.f;
#pragma unroll
    for (int t = 0; t < 24; ++t) s += red[j * 24 + t];
    attn[p] = s;
  }
}

__global__ void k_attn_final(const float* __restrict__ outvV, const float* __restrict__ vlb,
                             const float* __restrict__ coords, const unsigned* __restrict__ cnt,
                             float* __restrict__ attn, int n) {
  int p = blockIdx.x * 256 + threadIdx.x;
  if (p >= n) return;
  float a = attn[p] + vlb[0];
#pragma unroll
  for (int k = 0; k < 8; ++k) {
    int f; float w;
    corner_one(coords, cnt, p, k, f, w);
    a += w * outvV[f];
  }
  attn[p] = a;
}

// final stage: out = tanh(devox(outvUPD) + q@lwT[0:96] + (attn*h)@lwT[96:192] + lb)
__global__ __launch_bounds__(192) void k_devox_final(
    const float* __restrict__ outv, const float* __restrict__ q, const float* __restrict__ h,
    const float* __restrict__ attn, const float* __restrict__ lwT, const float* __restrict__ lb,
    const float* __restrict__ coords, const unsigned* __restrict__ cnt,
    float* __restrict__ dst, int n) {
  __shared__ int lflc[8][8];
  __shared__ float lcw[8][8];
  __shared__ float lq[8][CH], lctx[8][CH];
  int tid = threadIdx.x, p0 = blockIdx.x * 8;
  if (tid < 64) {
    int j = tid >> 3, k = tid & 7, p = p0 + j;
    int f = 0; float w = 0.f;
    if (p < n) corner_one(coords, cnt, p, k, f, w);
    lflc[j][k] = f; lcw[j][k] = w;
  }
  for (int e = tid; e < 8 * CH; e += 192) {
    int j = e / CH, c = e - j * CH; int p = p0 + j;
    if (p < n) {
      float av = attn[p];
      lq[j][c] = q[p * CH + c];
      lctx[j][c] = av * h[p * CH + c];
    } else {
      lq[j][c] = 0.f; lctx[j][c] = 0.f;
    }
  }
  __syncthreads();
  int j = tid / 24, lc = tid - j * 24, co0 = lc * 4;
  int p = p0 + j;
  float4 a = *reinterpret_cast<const float4*>(lb + co0);
#pragma unroll 4
  for (int ci = 0; ci < CH; ++ci) {
    float f = lq[j][ci];
    float4 w = *reinterpret_cast<const float4*>(lwT + ci * CH + co0);
    a.x += f * w.x; a.y += f * w.y; a.z += f * w.z; a.w += f * w.w;
  }
#pragma unroll 4
  for (int ci = 0; ci < CH; ++ci) {
    float f = lctx[j][ci];
    float4 w = *reinterpret_cast<const float4*>(lwT + (CH + ci) * CH + co0);
    a.x += f * w.x; a.y += f * w.y; a.z += f * w.z; a.w += f * w.w;
  }
#pragma unroll
  for (int k = 0; k < 8; ++k) {
    float w = lcw[j][k];
    float4 o = *reinterpret_cast<const float4*>(outv + lflc[j][k] * CH + co0);
    a.x += w * o.x; a.y += w * o.y; a.z += w * o.z; a.w += w * o.w;
  }
  if (p < n) {
    float4 r;
    r.x = tanhf(a.x); r.y = tanhf(a.y); r.z = tanhf(a.z); r.w = tanhf(a.w);
    *reinterpret_cast<float4*>(dst + p * CH + co0) = r;
  }
}

// ---------------- launch ----------------

extern "C" void kernel_launch(void* const* d_in, const int* in_sizes, int n_in,
                              void* d_out, int out_size, void* d_ws, size_t ws_size,
                              hipStream_t stream) {
  const float* hidden   = (const float*)d_in[0];
  const float* query    = (const float*)d_in[1];
  const float* coords   = (const float*)d_in[2];
  const float* wq_conv  = (const float*)d_in[3];
  const float* wq_lw    = (const float*)d_in[4];
  const float* wq_lb    = (const float*)d_in[5];
  const float* wh_conv  = (const float*)d_in[6];
  const float* wh_lw    = (const float*)d_in[7];
  const float* wh_lb    = (const float*)d_in[8];
  const float* att_conv = (const float*)d_in[9];
  const float* att_lw   = (const float*)d_in[10];
  const float* att_lb   = (const float*)d_in[11];
  const float* v_conv   = (const float*)d_in[12];
  const float* v_lw     = (const float*)d_in[13];
  const float* v_lb     = (const float*)d_in[14];
  const float* upd_conv = (const float*)d_in[15];
  const float* upd_lw   = (const float*)d_in[16];
  const float* upd_lb   = (const float*)d_in[17];
  float* out = (float*)d_out;
  const int n = in_sizes[0] / CH;

  char* wsp = (char*)d_ws;
  auto alloc = [&](size_t bytes) {
    char* r = wsp;
    wsp += (bytes + 255) & ~(size_t)255;
    return r;
  };
  int*      flat = (int*)     alloc((size_t)n * 4);
  unsigned* cnt  = (unsigned*)alloc((size_t)NV * 4);
  float*    inv  = (float*)   alloc((size_t)NV * 4);
  float*    attn = (float*)   alloc((size_t)n * 4);
  float* wtq  = (float*)alloc((size_t)27 * 96 * 96 * 4);
  float* wth  = (float*)alloc((size_t)27 * 96 * 96 * 4);
  float* wta  = (float*)alloc((size_t)27 * 192 * 96 * 4);
  float* wtv  = (float*)alloc((size_t)27 * 96 * 4);
  float* wtu  = (float*)alloc((size_t)27 * 192 * 96 * 4);
  float* lwqT = (float*)alloc((size_t)96 * 96 * 4);
  float* lwhT = (float*)alloc((size_t)96 * 96 * 4);
  float* lwaT = (float*)alloc((size_t)192 * 96 * 4);
  float* lwuT = (float*)alloc((size_t)192 * 96 * 4);
  float* G1 = (float*)alloc((size_t)NV * CH * 4);
  float* G2 = (float*)alloc((size_t)NV * CH * 4);
  float* O1 = (float*)alloc((size_t)NV * CH * 4);
  float* O2 = (float*)alloc((size_t)NV * CH * 4);
  float* qv = (float*)alloc((size_t)n * CH * 4);
  float* hv = (float*)alloc((size_t)n * CH * 4);

  const size_t gbytes = (size_t)NV * CH * 4;
  const int nb  = (n + 255) / 256;
  const int nbs = (n * CH + 255) / 256;
  const int ndv = (n + 7) / 8;

  // prep: voxel ids, counts, inverse counts; weight transposes
  hipMemsetAsync(cnt, 0, (size_t)NV * 4, stream);
  k_prep<<<nb, 256, 0, stream>>>(coords, flat, cnt, n);
  k_inv<<<(NV + 255) / 256, 256, 0, stream>>>(cnt, inv);
  k_tconv<<<(27*96*96 + 255)/256, 256, 0, stream>>>(wq_conv, wtq, 96, 96);
  k_tconv<<<(27*96*96 + 255)/256, 256, 0, stream>>>(wh_conv, wth, 96, 96);
  k_tconv<<<(27*192*96 + 255)/256, 256, 0, stream>>>(att_conv, wta, 96, 192);
  k_tconv<<<(27*96 + 255)/256, 256, 0, stream>>>(v_conv, wtv, 1, 96);
  k_tconv<<<(27*192*96 + 255)/256, 256, 0, stream>>>(upd_conv, wtu, 96, 192);
  k_tlin<<<(96*96 + 255)/256, 256, 0, stream>>>(wq_lw, lwqT, 96, 96);
  k_tlin<<<(96*96 + 255)/256, 256, 0, stream>>>(wh_lw, lwhT, 96, 96);
  k_tlin<<<(192*96 + 255)/256, 256, 0, stream>>>(att_lw, lwaT, 96, 192);
  k_tlin<<<(192*96 + 255)/256, 256, 0, stream>>>(upd_lw, lwuT, 96, 192);

  // stage 1: q = sconv(query)
  hipMemsetAsync(G1, 0, gbytes, stream);
  k_scatter<<<nbs, 256, 0, stream>>>(query, nullptr, flat, inv, G1, n);
  k_conv3d<1><<<1024, 256, 0, stream>>>(G1, G1, wtq, O1);
  k_devox_lin<<<ndv, 192, 0, stream>>>(O1, query, lwqT, wq_lb, coords, cnt, qv, n);

  // stage 2: h = sconv(hidden)
  hipMemsetAsync(G2, 0, gbytes, stream);
  k_scatter<<<nbs, 256, 0, stream>>>(hidden, nullptr, flat, inv, G2, n);
  k_conv3d<1><<<1024, 256, 0, stream>>>(G2, G2, wth, O2);
  k_devox_lin<<<ndv, 192, 0, stream>>>(O2, hidden, lwhT, wh_lb, coords, cnt, hv, n);

  // stage 3: energy = tanh(sconv([h,q])) -> scattered into G1 (voxE) + v-linear partial in attn
  hipMemsetAsync(G1, 0, gbytes, stream);
  hipMemsetAsync(G2, 0, gbytes, stream);
  k_scatter<<<nbs, 256, 0, stream>>>(hv, nullptr, flat, inv, G1, n);
  k_scatter<<<nbs, 256, 0, stream>>>(qv, nullptr, flat, inv, G2, n);   // G2 = vox(q), reused in stage 5
  k_conv3d<2><<<1024, 256, 0, stream>>>(G1, G2, wta, O1);
  hipMemsetAsync(G1, 0, gbytes, stream);                               // G1 becomes voxE
  k_devox_energy<<<ndv, 192, 0, stream>>>(O1, hv, qv, lwaT, att_lb, v_lw,
                                          coords, cnt, flat, inv, G1, attn, n);

  // stage 4: attn = sconv(energy) with Cout=1
  k_conv3d_v<<<1024, 128, 0, stream>>>(G1, wtv, O2);
  k_attn_final<<<nb, 256, 0, stream>>>(O2, v_lb, coords, cnt, attn, n);

  // stage 5: out = tanh(sconv([q, attn*h]))
  hipMemsetAsync(G1, 0, gbytes, stream);                               // G1 becomes vox(attn*h)
  k_scatter<<<nbs, 256, 0, stream>>>(hv, attn, flat, inv, G1, n);
  k_conv3d<2><<<1024, 256, 0, stream>>>(G2, G1, wtu, O1);
  k_devox_final<<<ndv, 192, 0, stream>>>(O1, qv, hv, attn, lwuT, upd_lb,
                                         coords, cnt, out, n);
}

// Round 3
// 1404.360 us; speedup vs baseline: 4.4745x; 2.3528x over previous
//
#include <hip/hip_runtime.h>
#include <math.h>

// AttenSeq2Seq on a sparse voxel grid. G=32, N=100000, C=96.
// R2: the four Cout=96 convs run as implicit-GEMM on v_mfma_f32_16x16x32_f16
// (f16 inputs, fp32 accum). Grids voxelized in fp32 (atomics), converted to
// f16; conv weights pre-packed on device into B-fragment lane order.
// Verified layouts (cdna docs): A[m=lane&15][k=(lane>>4)*8+j],
// B[k=(lane>>4)*8+j][n=lane&15], D[row=(lane>>4)*4+reg][col=lane&15].

#define GD 32
#define NV (GD*GD*GD)   // 32768 voxels
#define CH 96

typedef _Float16 half8 __attribute__((ext_vector_type(8)));
typedef float f32x4 __attribute__((ext_vector_type(4)));

// ---------------- small kernels ----------------

__global__ void k_prep(const float* __restrict__ coords, int* __restrict__ flat,
                       unsigned* __restrict__ cnt, int n) {
  int i = blockIdx.x * 256 + threadIdx.x;
  if (i >= n) return;
  float x = coords[3*i], y = coords[3*i+1], z = coords[3*i+2];
  int ix = (int)floorf(x); ix = ix < 0 ? 0 : (ix > 31 ? 31 : ix);
  int iy = (int)floorf(y); iy = iy < 0 ? 0 : (iy > 31 ? 31 : iy);
  int iz = (int)floorf(z); iz = iz < 0 ? 0 : (iz > 31 ? 31 : iz);
  int f = (ix << 10) + (iy << 5) + iz;
  flat[i] = f;
  atomicAdd(&cnt[f], 1u);
}

__global__ void k_inv(const unsigned* __restrict__ cnt, float* __restrict__ inv) {
  int v = blockIdx.x * 256 + threadIdx.x;
  if (v >= NV) return;
  unsigned c = cnt[v];
  inv[v] = c ? 1.0f / (float)c : 0.0f;
}

// conv weight (Co,Ci,27) -> (27,Ci,Co)  [used only for the Cout=1 v-conv]
__global__ void k_tconv(const float* __restrict__ w, float* __restrict__ wt, int Co, int Ci) {
  int e = blockIdx.x * 256 + threadIdx.x;
  int total = Co * Ci * 27;
  if (e >= total) return;
  int co = e % Co; int r = e / Co; int ci = r % Ci; int tap = r / Ci;
  wt[e] = w[(co * Ci + ci) * 27 + tap];
}

// lin weight (Co,Ci) -> (Ci,Co)
__global__ void k_tlin(const float* __restrict__ w, float* __restrict__ wt, int Co, int Ci) {
  int e = blockIdx.x * 256 + threadIdx.x;
  if (e >= Co * Ci) return;
  int co = e % Co; int ci = e / Co;
  wt[e] = w[co * Ci + ci];
}

// fp32 -> f16 grid conversion (4 elements/thread)
__global__ void k_tohalf(const float4* __restrict__ src, ushort4* __restrict__ dst, int n4) {
  int i = blockIdx.x * 256 + threadIdx.x;
  if (i >= n4) return;
  float4 v = src[i];
  union { _Float16 h; unsigned short u; } c0, c1, c2, c3;
  c0.h = (_Float16)v.x; c1.h = (_Float16)v.y; c2.h = (_Float16)v.z; c3.h = (_Float16)v.w;
  ushort4 o; o.x = c0.u; o.y = c1.u; o.z = c2.u; o.w = c3.u;
  dst[i] = o;
}

// pack conv weight (96, Ci, 27) fp32 -> f16 B-fragments:
// wp[tap][chunk][cotile(6)][lane(64)][j(8)] = W[co=cotile*16+(lane&15)][ci=chunk*32+(lane>>4)*8+j][tap]
__global__ void k_wpack(const float* __restrict__ w, _Float16* __restrict__ wp, int nch) {
  int e = blockIdx.x * 256 + threadIdx.x;
  int total = 27 * nch * 6 * 512;
  if (e >= total) return;
  int j = e & 7; int l = (e >> 3) & 63; int r = e >> 9;
  int cot = r % 6; r /= 6; int chk = r % nch; int tap = r / nch;
  int Ci = nch * 32;
  int ci = chk * 32 + (l >> 4) * 8 + j;
  int co = cot * 16 + (l & 15);
  wp[e] = (_Float16)w[(co * Ci + ci) * 27 + tap];
}

// scatter-mean: grid[flat[p]*96+ch] += feats[p,ch] * inv_cnt[flat[p]] * (scale?scale[p]:1)
__global__ void k_scatter(const float* __restrict__ feats, const float* __restrict__ scale,
                          const int* __restrict__ flat, const float* __restrict__ inv,
                          float* __restrict__ grid, int n) {
  int e = blockIdx.x * 256 + threadIdx.x;
  if (e >= n * CH) return;
  int p = e / CH, ch = e - p * CH;
  int f = flat[p];
  float v = feats[e] * inv[f];
  if (scale) v *= scale[p];
  atomicAdd(&grid[f * CH + ch], v);
}

// ---------------- MFMA 3x3x3 conv ----------------
// Block = 2 z-columns (x, y0), (x, y0+1); 4 waves = (column) x (co-half of 48).
// LDS: halo 12 cols x 34 z x 32 ci (f16, rows padded to 40) = 32640 B.
// K-loop: NCH ci-chunks x 27 taps; per tap 2 A-frags (m=32) x 3 B-frags (n=48).
template<int NCH>   // 3 (Cin=96) or 6 (Cin=192, second 96 from gB)
__global__ __launch_bounds__(256) void k_conv_mfma(
    const _Float16* __restrict__ gA, const _Float16* __restrict__ gB,
    const half8* __restrict__ wp, float* __restrict__ out) {
  __shared__ unsigned short ls[12 * 34 * 40];
  int bx = blockIdx.x >> 4, byq = blockIdx.x & 15;
  int y0 = byq * 2;
  int tid = threadIdx.x;
  int lane = tid & 63, wv = tid >> 6;
  int wcol = wv & 1, coh = wv >> 1;
  int lrow = lane & 15, quad = lane >> 4;

  f32x4 acc[2][3];
#pragma unroll
  for (int a = 0; a < 2; ++a)
#pragma unroll
    for (int b = 0; b < 3; ++b) acc[a][b] = (f32x4){0.f, 0.f, 0.f, 0.f};

  for (int chunk = 0; chunk < NCH; ++chunk) {
    const _Float16* g = (NCH == 6 && chunk >= 3) ? gB : gA;
    int cbase = ((NCH == 6 && chunk >= 3) ? chunk - 3 : chunk) * 32;
    __syncthreads();
    for (int e = tid; e < 12 * 34 * 4; e += 256) {
      int ciu = e & 3; int zc = e >> 2;
      int zz = zc % 34; int sc = zc / 34;
      int dx = sc >> 2, dyy = sc & 3;
      int x = bx + dx - 1, y = y0 + dyy - 1, zv = zz - 1;
      uint4 val = {0u, 0u, 0u, 0u};
      if ((unsigned)x < 32u && (unsigned)y < 32u && (unsigned)zv < 32u)
        val = *reinterpret_cast<const uint4*>(
            g + (size_t)((x << 10) + (y << 5) + zv) * CH + cbase + ciu * 8);
      *reinterpret_cast<uint4*>(&ls[(sc * 34 + zz) * 40 + ciu * 8]) = val;
    }
    __syncthreads();
#pragma unroll
    for (int dx9 = 0; dx9 < 3; ++dx9)
#pragma unroll
      for (int dy9 = 0; dy9 < 3; ++dy9) {
        int sc = dx9 * 4 + wcol + dy9;
        const unsigned short* lbase = &ls[sc * 34 * 40 + quad * 8];
        int tap0 = (dx9 * 3 + dy9) * 3;
#pragma unroll
        for (int dz = 0; dz < 3; ++dz) {
          half8 a0 = *reinterpret_cast<const half8*>(&lbase[(lrow + dz) * 40]);
          half8 a1 = *reinterpret_cast<const half8*>(&lbase[(lrow + dz + 16) * 40]);
          const half8* wb = wp + ((size_t)((tap0 + dz) * NCH + chunk) * 6 + coh * 3) * 64 + lane;
          half8 b0 = wb[0];
          half8 b1 = wb[64];
          half8 b2 = wb[128];
          acc[0][0] = __builtin_amdgcn_mfma_f32_16x16x32_f16(a0, b0, acc[0][0], 0, 0, 0);
          acc[1][0] = __builtin_amdgcn_mfma_f32_16x16x32_f16(a1, b0, acc[1][0], 0, 0, 0);
          acc[0][1] = __builtin_amdgcn_mfma_f32_16x16x32_f16(a0, b1, acc[0][1], 0, 0, 0);
          acc[1][1] = __builtin_amdgcn_mfma_f32_16x16x32_f16(a1, b1, acc[1][1], 0, 0, 0);
          acc[0][2] = __builtin_amdgcn_mfma_f32_16x16x32_f16(a0, b2, acc[0][2], 0, 0, 0);
          acc[1][2] = __builtin_amdgcn_mfma_f32_16x16x32_f16(a1, b2, acc[1][2], 0, 0, 0);
        }
      }
  }
  int y = y0 + wcol;
  int vb = (bx << 10) + (y << 5);
#pragma unroll
  for (int mf = 0; mf < 2; ++mf)
#pragma unroll
    for (int nt = 0; nt < 3; ++nt)
#pragma unroll
      for (int r = 0; r < 4; ++r) {
        int z = mf * 16 + quad * 4 + r;
        out[(size_t)(vb + z) * CH + coh * 48 + nt * 16 + lrow] = acc[mf][nt][r];
      }
}

// Cout=1 conv (the 'v' attention head), fp32. 128 thr: z = tid&31, 4 ci-partials.
__global__ __launch_bounds__(128) void k_conv3d_v(
    const float* __restrict__ g, const float* __restrict__ wt, float* __restrict__ out) {
  __shared__ float lg[9 * 34 * 33];
  __shared__ float red[128];
  int bx = blockIdx.x >> 5, by = blockIdx.x & 31;
  int tid = threadIdx.x;
  int z = tid & 31, part = tid >> 5;
  float acc = 0.f;
  for (int chunk = 0; chunk < 3; ++chunk) {
    int c0 = chunk * 32;
    __syncthreads();
    for (int e = tid; e < 9 * 34 * 32; e += 128) {
      int col = e / 1088; int rem = e - col * 1088;
      int zz = rem >> 5; int c = rem & 31;
      int x = bx + col / 3 - 1;
      int y = by + (col - (col / 3) * 3) - 1;
      int zv = zz - 1;
      float val = 0.f;
      if ((unsigned)x < 32u && (unsigned)y < 32u && (unsigned)zv < 32u)
        val = g[((x << 10) + (y << 5) + zv) * CH + c0 + c];
      lg[(col * 34 + zz) * 33 + c] = val;
    }
    __syncthreads();
    for (int tap = 0; tap < 27; ++tap) {
      int cc = tap / 3, dz = tap - cc * 3;
      const float* lgp = &lg[(cc * 34 + z + dz) * 33 + part * 8];
      const float* wp = wt + tap * CH + c0 + part * 8;
#pragma unroll
      for (int c = 0; c < 8; ++c) acc += lgp[c] * wp[c];
    }
  }
  red[tid] = acc;
  __syncthreads();
  if (part == 0)
    out[(bx << 10) + (by << 5) + z] = red[z] + red[z + 32] + red[z + 64] + red[z + 96];
}

// ---------------- trilinear devoxelize (+linear, + fusions) ----------------

__device__ __forceinline__ void corner_one(
    const float* __restrict__ coords, const unsigned* __restrict__ cnt,
    int p, int k, int& flc, float& w) {
  float cx = coords[3*p], cy = coords[3*p+1], cz = coords[3*p+2];
  float bx = floorf(cx), by = floorf(cy), bz = floorf(cz);
  float fx = cx - bx, fy = cy - by, fz = cz - bz;
  int dx = (k >> 2) & 1, dy = (k >> 1) & 1, dzz = k & 1;
  int ix = (int)bx + dx, iy = (int)by + dy, iz = (int)bz + dzz;
  bool valid = ((unsigned)ix < 32u) && ((unsigned)iy < 32u) && ((unsigned)iz < 32u);
  int xc = min(max(ix, 0), 31), yc = min(max(iy, 0), 31), zc = min(max(iz, 0), 31);
  flc = (xc << 10) + (yc << 5) + zc;
  float wx = dx ? fx : 1.f - fx;
  float wy = dy ? fy : 1.f - fy;
  float wz = dzz ? fz : 1.f - fz;
  w = (valid && cnt[flc] > 0u) ? wx * wy * wz : 0.f;
}

// 8 points/block, 24 co-threads x 4 co each. dst = devox(outv) + feats@lwT + lb
__global__ __launch_bounds__(192) void k_devox_lin(
    const float* __restrict__ outv, const float* __restrict__ feats,
    const float* __restrict__ lwT, const float* __restrict__ lb,
    const float* __restrict__ coords, const unsigned* __restrict__ cnt,
    float* __restrict__ dst, int n) {
  __shared__ int lflc[8][8];
  __shared__ float lcw[8][8];
  __shared__ float lf[8][CH];
  int tid = threadIdx.x, p0 = blockIdx.x * 8;
  if (tid < 64) {
    int j = tid >> 3, k = tid & 7, p = p0 + j;
    int f = 0; float w = 0.f;
    if (p < n) corner_one(coords, cnt, p, k, f, w);
    lflc[j][k] = f; lcw[j][k] = w;
  }
  for (int e = tid; e < 8 * CH; e += 192) {
    int j = e / CH, c = e - j * CH; int p = p0 + j;
    lf[j][c] = (p < n) ? feats[p * CH + c] : 0.f;
  }
  __syncthreads();
  int j = tid / 24, lc = tid - j * 24, co0 = lc * 4;
  int p = p0 + j;
  float4 a = *reinterpret_cast<const float4*>(lb + co0);
#pragma unroll 4
  for (int ci = 0; ci < CH; ++ci) {
    float f = lf[j][ci];
    float4 w = *reinterpret_cast<const float4*>(lwT + ci * CH + co0);
    a.x += f * w.x; a.y += f * w.y; a.z += f * w.z; a.w += f * w.w;
  }
#pragma unroll
  for (int k = 0; k < 8; ++k) {
    float w = lcw[j][k];
    float4 o = *reinterpret_cast<const float4*>(outv + lflc[j][k] * CH + co0);
    a.x += w * o.x; a.y += w * o.y; a.z += w * o.z; a.w += w * o.w;
  }
  if (p < n) *reinterpret_cast<float4*>(dst + p * CH + co0) = a;
}

// energy stage, fused: e = tanh(devox(outvATT) + h@lwT[0:96] + q@lwT[96:192] + lb);
// scatter e into voxE; attn[p] = sum_co e*v_lw[co] (v-linear partial).
__global__ __launch_bounds__(192) void k_devox_energy(
    const float* __restrict__ outv, const float* __restrict__ h, const float* __restrict__ q,
    const float* __restrict__ lwT, const float* __restrict__ lb, const float* __restrict__ vlw,
    const float* __restrict__ coords, const unsigned* __restrict__ cnt,
    const int* __restrict__ flat, const float* __restrict__ inv,
    float* __restrict__ voxE, float* __restrict__ attn, int n) {
  __shared__ int lflc[8][8];
  __shared__ float lcw[8][8];
  __shared__ float lh[8][CH], lq[8][CH];
  __shared__ float red[192];
  int tid = threadIdx.x, p0 = blockIdx.x * 8;
  if (tid < 64) {
    int j = tid >> 3, k = tid & 7, p = p0 + j;
    int f = 0; float w = 0.f;
    if (p < n) corner_one(coords, cnt, p, k, f, w);
    lflc[j][k] = f; lcw[j][k] = w;
  }
  for (int e = tid; e < 8 * CH; e += 192) {
    int j = e / CH, c = e - j * CH; int p = p0 + j;
    lh[j][c] = (p < n) ? h[p * CH + c] : 0.f;
    lq[j][c] = (p < n) ? q[p * CH + c] : 0.f;
  }
  __syncthreads();
  int j = tid / 24, lc = tid - j * 24, co0 = lc * 4;
  int p = p0 + j;
  float4 a = *reinterpret_cast<const float4*>(lb + co0);
#pragma unroll 4
  for (int ci = 0; ci < CH; ++ci) {
    float f = lh[j][ci];
    float4 w = *reinterpret_cast<const float4*>(lwT + ci * CH + co0);
    a.x += f * w.x; a.y += f * w.y; a.z += f * w.z; a.w += f * w.w;
  }
#pragma unroll 4
  for (int ci = 0; ci < CH; ++ci) {
    float f = lq[j][ci];
    float4 w = *reinterpret_cast<const float4*>(lwT + (CH + ci) * CH + co0);
    a.x += f * w.x; a.y += f * w.y; a.z += f * w.z; a.w += f * w.w;
  }
#pragma unroll
  for (int k = 0; k < 8; ++k) {
    float w = lcw[j][k];
    float4 o = *reinterpret_cast<const float4*>(outv + lflc[j][k] * CH + co0);
    a.x += w * o.x; a.y += w * o.y; a.z += w * o.z; a.w += w * o.w;
  }
  float e0 = tanhf(a.x), e1 = tanhf(a.y), e2 = tanhf(a.z), e3 = tanhf(a.w);
  if (p < n) {
    int f = flat[p]; float iv = inv[f];
    float* vb = voxE + f * CH + co0;
    atomicAdd(vb + 0, e0 * iv); atomicAdd(vb + 1, e1 * iv);
    atomicAdd(vb + 2, e2 * iv); atomicAdd(vb + 3, e3 * iv);
  }
  float4 vw = *reinterpret_cast<const float4*>(vlw + co0);
  red[tid] = e0 * vw.x + e1 * vw.y + e2 * vw.z + e3 * vw.w;
  __syncthreads();
  if (lc == 0 && p < n) {
    float s = 0.f;
#pragma unroll
    for (int t = 0; t < 24; ++t) s += red[j * 24 + t];
    attn[p] = s;
  }
}

__global__ void k_attn_final(const float* __restrict__ outvV, const float* __restrict__ vlb,
                             const float* __restrict__ coords, const unsigned* __restrict__ cnt,
                             float* __restrict__ attn, int n) {
  int p = blockIdx.x * 256 + threadIdx.x;
  if (p >= n) return;
  float a = attn[p] + vlb[0];
#pragma unroll
  for (int k = 0; k < 8; ++k) {
    int f; float w;
    corner_one(coords, cnt, p, k, f, w);
    a += w * outvV[f];
  }
  attn[p] = a;
}

// final stage: out = tanh(devox(outvUPD) + q@lwT[0:96] + (attn*h)@lwT[96:192] + lb)
__global__ __launch_bounds__(192) void k_devox_final(
    const float* __restrict__ outv, const float* __restrict__ q, const float* __restrict__ h,
    const float* __restrict__ attn, const float* __restrict__ lwT, const float* __restrict__ lb,
    const float* __restrict__ coords, const unsigned* __restrict__ cnt,
    float* __restrict__ dst, int n) {
  __shared__ int lflc[8][8];
  __shared__ float lcw[8][8];
  __shared__ float lq[8][CH], lctx[8][CH];
  int tid = threadIdx.x, p0 = blockIdx.x * 8;
  if (tid < 64) {
    int j = tid >> 3, k = tid & 7, p = p0 + j;
    int f = 0; float w = 0.f;
    if (p < n) corner_one(coords, cnt, p, k, f, w);
    lflc[j][k] = f; lcw[j][k] = w;
  }
  for (int e = tid; e < 8 * CH; e += 192) {
    int j = e / CH, c = e - j * CH; int p = p0 + j;
    if (p < n) {
      float av = attn[p];
      lq[j][c] = q[p * CH + c];
      lctx[j][c] = av * h[p * CH + c];
    } else {
      lq[j][c] = 0.f; lctx[j][c] = 0.f;
    }
  }
  __syncthreads();
  int j = tid / 24, lc = tid - j * 24, co0 = lc * 4;
  int p = p0 + j;
  float4 a = *reinterpret_cast<const float4*>(lb + co0);
#pragma unroll 4
  for (int ci = 0; ci < CH; ++ci) {
    float f = lq[j][ci];
    float4 w = *reinterpret_cast<const float4*>(lwT + ci * CH + co0);
    a.x += f * w.x; a.y += f * w.y; a.z += f * w.z; a.w += f * w.w;
  }
#pragma unroll 4
  for (int ci = 0; ci < CH; ++ci) {
    float f = lctx[j][ci];
    float4 w = *reinterpret_cast<const float4*>(lwT + (CH + ci) * CH + co0);
    a.x += f * w.x; a.y += f * w.y; a.z += f * w.z; a.w += f * w.w;
  }
#pragma unroll
  for (int k = 0; k < 8; ++k) {
    float w = lcw[j][k];
    float4 o = *reinterpret_cast<const float4*>(outv + lflc[j][k] * CH + co0);
    a.x += w * o.x; a.y += w * o.y; a.z += w * o.z; a.w += w * o.w;
  }
  if (p < n) {
    float4 r;
    r.x = tanhf(a.x); r.y = tanhf(a.y); r.z = tanhf(a.z); r.w = tanhf(a.w);
    *reinterpret_cast<float4*>(dst + p * CH + co0) = r;
  }
}

// ---------------- launch ----------------

extern "C" void kernel_launch(void* const* d_in, const int* in_sizes, int n_in,
                              void* d_out, int out_size, void* d_ws, size_t ws_size,
                              hipStream_t stream) {
  const float* hidden   = (const float*)d_in[0];
  const float* query    = (const float*)d_in[1];
  const float* coords   = (const float*)d_in[2];
  const float* wq_conv  = (const float*)d_in[3];
  const float* wq_lw    = (const float*)d_in[4];
  const float* wq_lb    = (const float*)d_in[5];
  const float* wh_conv  = (const float*)d_in[6];
  const float* wh_lw    = (const float*)d_in[7];
  const float* wh_lb    = (const float*)d_in[8];
  const float* att_conv = (const float*)d_in[9];
  const float* att_lw   = (const float*)d_in[10];
  const float* att_lb   = (const float*)d_in[11];
  const float* v_conv   = (const float*)d_in[12];
  const float* v_lw     = (const float*)d_in[13];
  const float* v_lb     = (const float*)d_in[14];
  const float* upd_conv = (const float*)d_in[15];
  const float* upd_lw   = (const float*)d_in[16];
  const float* upd_lb   = (const float*)d_in[17];
  float* out = (float*)d_out;
  const int n = in_sizes[0] / CH;

  char* wsp = (char*)d_ws;
  auto alloc = [&](size_t bytes) {
    char* r = wsp;
    wsp += (bytes + 255) & ~(size_t)255;
    return r;
  };
  int*      flat = (int*)     alloc((size_t)n * 4);
  unsigned* cnt  = (unsigned*)alloc((size_t)NV * 4);
  float*    inv  = (float*)   alloc((size_t)NV * 4);
  float*    attn = (float*)   alloc((size_t)n * 4);
  float* wtv  = (float*)alloc((size_t)27 * 96 * 4);
  _Float16* wpq = (_Float16*)alloc((size_t)27 * 3 * 6 * 512 * 2);
  _Float16* wph = (_Float16*)alloc((size_t)27 * 3 * 6 * 512 * 2);
  _Float16* wpa = (_Float16*)alloc((size_t)27 * 6 * 6 * 512 * 2);
  _Float16* wpu = (_Float16*)alloc((size_t)27 * 6 * 6 * 512 * 2);
  float* lwqT = (float*)alloc((size_t)96 * 96 * 4);
  float* lwhT = (float*)alloc((size_t)96 * 96 * 4);
  float* lwaT = (float*)alloc((size_t)192 * 96 * 4);
  float* lwuT = (float*)alloc((size_t)192 * 96 * 4);
  float* G1 = (float*)alloc((size_t)NV * CH * 4);
  float* G2 = (float*)alloc((size_t)NV * CH * 4);
  _Float16* H1 = (_Float16*)alloc((size_t)NV * CH * 2);
  _Float16* H2 = (_Float16*)alloc((size_t)NV * CH * 2);
  float* O1 = (float*)alloc((size_t)NV * CH * 4);
  float* O2 = (float*)alloc((size_t)NV * CH * 4);
  float* qv = (float*)alloc((size_t)n * CH * 4);
  float* hv = (float*)alloc((size_t)n * CH * 4);

  const size_t gbytes = (size_t)NV * CH * 4;
  const int nb  = (n + 255) / 256;
  const int nbs = (n * CH + 255) / 256;
  const int ndv = (n + 7) / 8;
  const int n4  = NV * CH / 4;
  const int nb4 = (n4 + 255) / 256;

  // prep: voxel ids, counts; weight transforms
  hipMemsetAsync(cnt, 0, (size_t)NV * 4, stream);
  k_prep<<<nb, 256, 0, stream>>>(coords, flat, cnt, n);
  k_inv<<<(NV + 255) / 256, 256, 0, stream>>>(cnt, inv);
  k_tconv<<<(27*96 + 255)/256, 256, 0, stream>>>(v_conv, wtv, 1, 96);
  k_wpack<<<(27*3*6*512 + 255)/256, 256, 0, stream>>>(wq_conv, wpq, 3);
  k_wpack<<<(27*3*6*512 + 255)/256, 256, 0, stream>>>(wh_conv, wph, 3);
  k_wpack<<<(27*6*6*512 + 255)/256, 256, 0, stream>>>(att_conv, wpa, 6);
  k_wpack<<<(27*6*6*512 + 255)/256, 256, 0, stream>>>(upd_conv, wpu, 6);
  k_tlin<<<(96*96 + 255)/256, 256, 0, stream>>>(wq_lw, lwqT, 96, 96);
  k_tlin<<<(96*96 + 255)/256, 256, 0, stream>>>(wh_lw, lwhT, 96, 96);
  k_tlin<<<(192*96 + 255)/256, 256, 0, stream>>>(att_lw, lwaT, 96, 192);
  k_tlin<<<(192*96 + 255)/256, 256, 0, stream>>>(upd_lw, lwuT, 96, 192);

  // stage 1: q = sconv(query)
  hipMemsetAsync(G1, 0, gbytes, stream);
  k_scatter<<<nbs, 256, 0, stream>>>(query, nullptr, flat, inv, G1, n);
  k_tohalf<<<nb4, 256, 0, stream>>>((const float4*)G1, (ushort4*)H1, n4);
  k_conv_mfma<3><<<512, 256, 0, stream>>>(H1, H1, (const half8*)wpq, O1);
  k_devox_lin<<<ndv, 192, 0, stream>>>(O1, query, lwqT, wq_lb, coords, cnt, qv, n);

  // stage 2: h = sconv(hidden)
  hipMemsetAsync(G1, 0, gbytes, stream);
  k_scatter<<<nbs, 256, 0, stream>>>(hidden, nullptr, flat, inv, G1, n);
  k_tohalf<<<nb4, 256, 0, stream>>>((const float4*)G1, (ushort4*)H2, n4);
  k_conv_mfma<3><<<512, 256, 0, stream>>>(H2, H2, (const half8*)wph, O2);
  k_devox_lin<<<ndv, 192, 0, stream>>>(O2, hidden, lwhT, wh_lb, coords, cnt, hv, n);

  // stage 3: energy = tanh(sconv([h,q])) -> voxE (G1) + v-linear partial (attn)
  hipMemsetAsync(G1, 0, gbytes, stream);
  hipMemsetAsync(G2, 0, gbytes, stream);
  k_scatter<<<nbs, 256, 0, stream>>>(hv, nullptr, flat, inv, G1, n);
  k_scatter<<<nbs, 256, 0, stream>>>(qv, nullptr, flat, inv, G2, n);
  k_tohalf<<<nb4, 256, 0, stream>>>((const float4*)G1, (ushort4*)H1, n4);   // H1 = vox(h)
  k_tohalf<<<nb4, 256, 0, stream>>>((const float4*)G2, (ushort4*)H2, n4);   // H2 = vox(q), reused stage 5
  k_conv_mfma<6><<<512, 256, 0, stream>>>(H1, H2, (const half8*)wpa, O1);
  hipMemsetAsync(G1, 0, gbytes, stream);                                    // G1 becomes voxE (fp32)
  k_devox_energy<<<ndv, 192, 0, stream>>>(O1, hv, qv, lwaT, att_lb, v_lw,
                                          coords, cnt, flat, inv, G1, attn, n);

  // stage 4: attn = sconv(energy) with Cout=1 (fp32 path)
  k_conv3d_v<<<1024, 128, 0, stream>>>(G1, wtv, O2);
  k_attn_final<<<nb, 256, 0, stream>>>(O2, v_lb, coords, cnt, attn, n);

  // stage 5: out = tanh(sconv([q, attn*h]))
  hipMemsetAsync(G2, 0, gbytes, stream);
  k_scatter<<<nbs, 256, 0, stream>>>(hv, attn, flat, inv, G2, n);           // G2 = vox(attn*h)
  k_tohalf<<<nb4, 256, 0, stream>>>((const float4*)G2, (ushort4*)H1, n4);   // H1 = vox(attn*h)
  k_conv_mfma<6><<<512, 256, 0, stream>>>(H2, H1, (const half8*)wpu, O1);
  k_devox_final<<<ndv, 192, 0, stream>>>(O1, qv, hv, attn, lwuT, upd_lb,
                                         coords, cnt, out, n);
}

// Round 4
// 851.712 us; speedup vs baseline: 7.3779x; 1.6489x over previous
//
#include <hip/hip_runtime.h>
#include <math.h>

// AttenSeq2Seq on a sparse voxel grid. G=32, N=100000, C=96.
// R3: (a) point-side linears run on MFMA with LDS-staged A and packed B-frags
// (kills the 7.3GB/dispatch L1/L2 weight refetch of the old devox kernels);
// (b) CSR voxelization (count/scan/fill) turns every scatter-mean into a
// voxel-parallel gather writing f16 grids directly — no 96ch atomics, no grid
// memsets, no fp32->f16 passes.
// MFMA layouts (verified): A[m=lane&15][k=(lane>>4)*8+j],
// B[k=(lane>>4)*8+j][n=lane&15], D[row=(lane>>4)*4+reg][col=lane&15].

#define GD 32
#define NV (GD*GD*GD)   // 32768 voxels
#define CH 96

typedef _Float16 half8 __attribute__((ext_vector_type(8)));
typedef float f32x4 __attribute__((ext_vector_type(4)));

// ---------------- prep / CSR ----------------

__global__ void k_prep(const float* __restrict__ coords, int* __restrict__ flat,
                       unsigned* __restrict__ cnt, int n) {
  int i = blockIdx.x * 256 + threadIdx.x;
  if (i >= n) return;
  float x = coords[3*i], y = coords[3*i+1], z = coords[3*i+2];
  int ix = (int)floorf(x); ix = ix < 0 ? 0 : (ix > 31 ? 31 : ix);
  int iy = (int)floorf(y); iy = iy < 0 ? 0 : (iy > 31 ? 31 : iy);
  int iz = (int)floorf(z); iz = iz < 0 ? 0 : (iz > 31 ? 31 : iz);
  int f = (ix << 10) + (iy << 5) + iz;
  flat[i] = f;
  atomicAdd(&cnt[f], 1u);
}

// single-block exclusive scan of cnt[NV] -> base, cur; also inv = 1/cnt.
__global__ __launch_bounds__(1024) void k_scan(
    const unsigned* __restrict__ cnt, unsigned* __restrict__ base,
    unsigned* __restrict__ cur, float* __restrict__ inv) {
  __shared__ unsigned part[1024];
  int tid = threadIdx.x;
  int b0 = tid * 32;
  unsigned s = 0;
  for (int i = 0; i < 32; ++i) s += cnt[b0 + i];
  part[tid] = s;
  __syncthreads();
  for (int off = 1; off < 1024; off <<= 1) {
    unsigned t = (tid >= off) ? part[tid - off] : 0u;
    __syncthreads();
    if (tid >= off) part[tid] += t;
    __syncthreads();
  }
  unsigned run = part[tid] - s;   // exclusive base of this chunk
  for (int i = 0; i < 32; ++i) {
    int v = b0 + i;
    unsigned c = cnt[v];
    base[v] = run; cur[v] = run;
    inv[v] = c ? 1.0f / (float)c : 0.0f;
    run += c;
  }
}

__global__ void k_fill(const int* __restrict__ flat, unsigned* __restrict__ cur,
                       int* __restrict__ order, int n) {
  int p = blockIdx.x * 256 + threadIdx.x;
  if (p >= n) return;
  unsigned pos = atomicAdd(&cur[flat[p]], 1u);
  order[pos] = p;
}

// voxel-gather mean: grid[v][:] = (1/cnt) * sum_{p in voxel} src[p][:] * (scale?scale[p]:1)
// OUTF16=1 -> f16 grid; else fp32 grid. Thread = (voxel, float4-chunk of 24).
template<int OUTF16, int SCALED>
__global__ void k_voxavg(const float4* __restrict__ src, const float* __restrict__ scale,
                         const unsigned* __restrict__ base, const unsigned* __restrict__ cnt,
                         const float* __restrict__ inv, const int* __restrict__ order,
                         void* __restrict__ dst) {
  int e = blockIdx.x * 256 + threadIdx.x;   // e < NV*24
  int v = e / 24, c4 = e - v * 24;
  unsigned b = base[v], c = cnt[v];
  float4 s = {0.f, 0.f, 0.f, 0.f};
  for (unsigned i = 0; i < c; ++i) {
    int p = order[b + i];
    float4 x = src[p * 24 + c4];
    if (SCALED) {
      float sc = scale[p];
      x.x *= sc; x.y *= sc; x.z *= sc; x.w *= sc;
    }
    s.x += x.x; s.y += x.y; s.z += x.z; s.w += x.w;
  }
  float iv = inv[v];
  s.x *= iv; s.y *= iv; s.z *= iv; s.w *= iv;
  if (OUTF16) {
    union { _Float16 h; unsigned short u; } h0, h1, h2, h3;
    h0.h = (_Float16)s.x; h1.h = (_Float16)s.y; h2.h = (_Float16)s.z; h3.h = (_Float16)s.w;
    ushort4 o; o.x = h0.u; o.y = h1.u; o.z = h2.u; o.w = h3.u;
    reinterpret_cast<ushort4*>(dst)[e] = o;
  } else {
    reinterpret_cast<float4*>(dst)[e] = s;
  }
}

// ---------------- weight packing ----------------

// conv weight (Co,Ci,27) -> (27,Ci,Co) fp32  [only for the Cout=1 v-conv]
__global__ void k_tconv(const float* __restrict__ w, float* __restrict__ wt, int Co, int Ci) {
  int e = blockIdx.x * 256 + threadIdx.x;
  int total = Co * Ci * 27;
  if (e >= total) return;
  int co = e % Co; int r = e / Co; int ci = r % Ci; int tap = r / Ci;
  wt[e] = w[(co * Ci + ci) * 27 + tap];
}

// conv weight (96, Ci, 27) fp32 -> f16 B-frags [tap][chunk][cotile6][lane][8]
__global__ void k_wpack(const float* __restrict__ w, _Float16* __restrict__ wp, int nch) {
  int e = blockIdx.x * 256 + threadIdx.x;
  int total = 27 * nch * 6 * 512;
  if (e >= total) return;
  int j = e & 7; int l = (e >> 3) & 63; int r = e >> 9;
  int cot = r % 6; r /= 6; int chk = r % nch; int tap = r / nch;
  int Ci = nch * 32;
  int ci = chk * 32 + (l >> 4) * 8 + j;
  int co = cot * 16 + (l & 15);
  wp[e] = (_Float16)w[(co * Ci + ci) * 27 + tap];
}

// linear weight (96, Ci) fp32 -> f16 B-frags [ktile][ntile6][lane][8]
__global__ void k_linpack(const float* __restrict__ w, _Float16* __restrict__ wl, int kb) {
  int e = blockIdx.x * 256 + threadIdx.x;
  int total = kb * 6 * 512;
  if (e >= total) return;
  int j = e & 7; int l = (e >> 3) & 63; int r = e >> 9;
  int nt = r % 6; int kt = r / 6;
  int Ci = kb * 32;
  int ci = kt * 32 + (l >> 4) * 8 + j;
  int co = nt * 16 + (l & 15);
  wl[e] = (_Float16)w[co * Ci + ci];
}

// ---------------- MFMA 3x3x3 conv (unchanged from R2) ----------------
template<int NCH>   // 3 (Cin=96) or 6 (Cin=192, second 96 from gB)
__global__ __launch_bounds__(256) void k_conv_mfma(
    const _Float16* __restrict__ gA, const _Float16* __restrict__ gB,
    const half8* __restrict__ wp, float* __restrict__ out) {
  __shared__ unsigned short ls[12 * 34 * 40];
  int bx = blockIdx.x >> 4, byq = blockIdx.x & 15;
  int y0 = byq * 2;
  int tid = threadIdx.x;
  int lane = tid & 63, wv = tid >> 6;
  int wcol = wv & 1, coh = wv >> 1;
  int lrow = lane & 15, quad = lane >> 4;

  f32x4 acc[2][3];
#pragma unroll
  for (int a = 0; a < 2; ++a)
#pragma unroll
    for (int b = 0; b < 3; ++b) acc[a][b] = (f32x4){0.f, 0.f, 0.f, 0.f};

  for (int chunk = 0; chunk < NCH; ++chunk) {
    const _Float16* g = (NCH == 6 && chunk >= 3) ? gB : gA;
    int cbase = ((NCH == 6 && chunk >= 3) ? chunk - 3 : chunk) * 32;
    __syncthreads();
    for (int e = tid; e < 12 * 34 * 4; e += 256) {
      int ciu = e & 3; int zc = e >> 2;
      int zz = zc % 34; int sc = zc / 34;
      int dx = sc >> 2, dyy = sc & 3;
      int x = bx + dx - 1, y = y0 + dyy - 1, zv = zz - 1;
      uint4 val = {0u, 0u, 0u, 0u};
      if ((unsigned)x < 32u && (unsigned)y < 32u && (unsigned)zv < 32u)
        val = *reinterpret_cast<const uint4*>(
            g + (size_t)((x << 10) + (y << 5) + zv) * CH + cbase + ciu * 8);
      *reinterpret_cast<uint4*>(&ls[(sc * 34 + zz) * 40 + ciu * 8]) = val;
    }
    __syncthreads();
#pragma unroll
    for (int dx9 = 0; dx9 < 3; ++dx9)
#pragma unroll
      for (int dy9 = 0; dy9 < 3; ++dy9) {
        int sc = dx9 * 4 + wcol + dy9;
        const unsigned short* lbase = &ls[sc * 34 * 40 + quad * 8];
        int tap0 = (dx9 * 3 + dy9) * 3;
#pragma unroll
        for (int dz = 0; dz < 3; ++dz) {
          half8 a0 = *reinterpret_cast<const half8*>(&lbase[(lrow + dz) * 40]);
          half8 a1 = *reinterpret_cast<const half8*>(&lbase[(lrow + dz + 16) * 40]);
          const half8* wb = wp + ((size_t)((tap0 + dz) * NCH + chunk) * 6 + coh * 3) * 64 + lane;
          half8 b0 = wb[0];
          half8 b1 = wb[64];
          half8 b2 = wb[128];
          acc[0][0] = __builtin_amdgcn_mfma_f32_16x16x32_f16(a0, b0, acc[0][0], 0, 0, 0);
          acc[1][0] = __builtin_amdgcn_mfma_f32_16x16x32_f16(a1, b0, acc[1][0], 0, 0, 0);
          acc[0][1] = __builtin_amdgcn_mfma_f32_16x16x32_f16(a0, b1, acc[0][1], 0, 0, 0);
          acc[1][1] = __builtin_amdgcn_mfma_f32_16x16x32_f16(a1, b1, acc[1][1], 0, 0, 0);
          acc[0][2] = __builtin_amdgcn_mfma_f32_16x16x32_f16(a0, b2, acc[0][2], 0, 0, 0);
          acc[1][2] = __builtin_amdgcn_mfma_f32_16x16x32_f16(a1, b2, acc[1][2], 0, 0, 0);
        }
      }
  }
  int y = y0 + wcol;
  int vb = (bx << 10) + (y << 5);
#pragma unroll
  for (int mf = 0; mf < 2; ++mf)
#pragma unroll
    for (int nt = 0; nt < 3; ++nt)
#pragma unroll
      for (int r = 0; r < 4; ++r) {
        int z = mf * 16 + quad * 4 + r;
        out[(size_t)(vb + z) * CH + coh * 48 + nt * 16 + lrow] = acc[mf][nt][r];
      }
}

// Cout=1 conv (the 'v' attention head), fp32.
__global__ __launch_bounds__(128) void k_conv3d_v(
    const float* __restrict__ g, const float* __restrict__ wt, float* __restrict__ out) {
  __shared__ float lg[9 * 34 * 33];
  __shared__ float red[128];
  int bx = blockIdx.x >> 5, by = blockIdx.x & 31;
  int tid = threadIdx.x;
  int z = tid & 31, part = tid >> 5;
  float acc = 0.f;
  for (int chunk = 0; chunk < 3; ++chunk) {
    int c0 = chunk * 32;
    __syncthreads();
    for (int e = tid; e < 9 * 34 * 32; e += 128) {
      int col = e / 1088; int rem = e - col * 1088;
      int zz = rem >> 5; int c = rem & 31;
      int x = bx + col / 3 - 1;
      int y = by + (col - (col / 3) * 3) - 1;
      int zv = zz - 1;
      float val = 0.f;
      if ((unsigned)x < 32u && (unsigned)y < 32u && (unsigned)zv < 32u)
        val = g[((x << 10) + (y << 5) + zv) * CH + c0 + c];
      lg[(col * 34 + zz) * 33 + c] = val;
    }
    __syncthreads();
    for (int tap = 0; tap < 27; ++tap) {
      int cc = tap / 3, dz = tap - cc * 3;
      const float* lgp = &lg[(cc * 34 + z + dz) * 33 + part * 8];
      const float* wp = wt + tap * CH + c0 + part * 8;
#pragma unroll
      for (int c = 0; c < 8; ++c) acc += lgp[c] * wp[c];
    }
  }
  red[tid] = acc;
  __syncthreads();
  if (part == 0)
    out[(bx << 10) + (by << 5) + z] = red[z] + red[z + 32] + red[z + 64] + red[z + 96];
}

// ---------------- fused point kernel: MFMA linear + trilinear devox ----------------

__device__ __forceinline__ void corner_one(
    const float* __restrict__ coords, const unsigned* __restrict__ cnt,
    int p, int k, int& flc, float& w) {
  float cx = coords[3*p], cy = coords[3*p+1], cz = coords[3*p+2];
  float bx = floorf(cx), by = floorf(cy), bz = floorf(cz);
  float fx = cx - bx, fy = cy - by, fz = cz - bz;
  int dx = (k >> 2) & 1, dy = (k >> 1) & 1, dzz = k & 1;
  int ix = (int)bx + dx, iy = (int)by + dy, iz = (int)bz + dzz;
  bool valid = ((unsigned)ix < 32u) && ((unsigned)iy < 32u) && ((unsigned)iz < 32u);
  int xc = min(max(ix, 0), 31), yc = min(max(iy, 0), 31), zc = min(max(iz, 0), 31);
  flc = (xc << 10) + (yc << 5) + zc;
  float wx = dx ? fx : 1.f - fx;
  float wy = dy ? fy : 1.f - fy;
  float wz = dzz ? fz : 1.f - fz;
  w = (valid && cnt[flc] > 0u) ? wx * wy * wz : 0.f;
}

// KB: 3 (K=96) or 6 (K=192, X = [X1, X2]).
// MODE: 0 = plain (dst = devox+lin+b), 1 = energy (tanh, + attn partial = e.vlw),
//       2 = final (tanh; X2 scaled by `scale` during staging).
// 64 points/block, 256 threads (4 waves = 4 m-tiles of 16 points).
template<int KB, int MODE>
__global__ __launch_bounds__(256) void k_point(
    const float* __restrict__ outv, const float* __restrict__ X1, const float* __restrict__ X2,
    const float* __restrict__ scale, const half8* __restrict__ wl,
    const float* __restrict__ lb, const float* __restrict__ vlw,
    const float* __restrict__ coords, const unsigned* __restrict__ cnt,
    float* __restrict__ dst, float* __restrict__ attn_out, int n) {
  __shared__ char us[64 * 100 * 4];   // union: f16 A-stage [64][KB*32+8] / fp32 acc [64][100]
  __shared__ int lflc[512];
  __shared__ float lcw[512];
  constexpr int APITCH = KB * 32 + 8;
  int tid = threadIdx.x;
  int p0 = blockIdx.x * 64;

  // corner table
  for (int e = tid; e < 512; e += 256) {
    int j = e >> 3, k = e & 7, p = p0 + j;
    int f = 0; float w = 0.f;
    if (p < n) corner_one(coords, cnt, p, k, f, w);
    lflc[e] = f; lcw[e] = w;
  }

  // stage A (f16) into LDS
  unsigned short* lsa = reinterpret_cast<unsigned short*>(us);
  constexpr int T4 = 64 * KB * 8;
  for (int e = tid; e < T4; e += 256) {
    int j = e / (KB * 8);
    int q4 = e - j * (KB * 8);
    int p = p0 + j;
    float4 v = {0.f, 0.f, 0.f, 0.f};
    if (p < n) {
      if (KB == 3 || q4 < 24) {
        v = reinterpret_cast<const float4*>(X1)[p * 24 + q4];
      } else {
        v = reinterpret_cast<const float4*>(X2)[p * 24 + (q4 - 24)];
        if (MODE == 2) {
          float sc = scale[p];
          v.x *= sc; v.y *= sc; v.z *= sc; v.w *= sc;
        }
      }
    }
    union { _Float16 h; unsigned short u; } h0, h1, h2, h3;
    h0.h = (_Float16)v.x; h1.h = (_Float16)v.y; h2.h = (_Float16)v.z; h3.h = (_Float16)v.w;
    ushort4 o; o.x = h0.u; o.y = h1.u; o.z = h2.u; o.w = h3.u;
    *reinterpret_cast<ushort4*>(&lsa[j * APITCH + q4 * 4]) = o;
  }
  __syncthreads();

  // MFMA: wave wv handles points [wv*16, wv*16+16), full N=96.
  int lane = tid & 63, wv = tid >> 6;
  int lrow = lane & 15, quad = lane >> 4;
  f32x4 acc[6];
#pragma unroll
  for (int i = 0; i < 6; ++i) acc[i] = (f32x4){0.f, 0.f, 0.f, 0.f};
#pragma unroll
  for (int kt = 0; kt < KB; ++kt) {
    half8 a = *reinterpret_cast<const half8*>(&lsa[(wv * 16 + lrow) * APITCH + kt * 32 + quad * 8]);
    const half8* wb = wl + (size_t)(kt * 6) * 64 + lane;
#pragma unroll
    for (int nt = 0; nt < 6; ++nt)
      acc[nt] = __builtin_amdgcn_mfma_f32_16x16x32_f16(a, wb[(size_t)nt * 64], acc[nt], 0, 0, 0);
  }
  __syncthreads();   // done reading lsa; reuse as fp32 acc
  float* lacc = reinterpret_cast<float*>(us);
#pragma unroll
  for (int nt = 0; nt < 6; ++nt)
#pragma unroll
    for (int r = 0; r < 4; ++r)
      lacc[(wv * 16 + quad * 4 + r) * 100 + nt * 16 + lrow] = acc[nt][r];
  __syncthreads();

  // point-major epilogue: 4 threads/point x 24 channels.
  int pt = tid >> 2, sub = tid & 3;
  int p = p0 + pt;
  float4 a[6];
  const float* lrow_p = &lacc[pt * 100 + sub * 24];
#pragma unroll
  for (int i = 0; i < 6; ++i) a[i] = *reinterpret_cast<const float4*>(lrow_p + i * 4);
  const float4* lb4 = reinterpret_cast<const float4*>(lb + sub * 24);
#pragma unroll
  for (int i = 0; i < 6; ++i) {
    float4 b = lb4[i];
    a[i].x += b.x; a[i].y += b.y; a[i].z += b.z; a[i].w += b.w;
  }
#pragma unroll
  for (int k = 0; k < 8; ++k) {
    float w = lcw[pt * 8 + k];
    if (w != 0.f) {
      const float4* op = reinterpret_cast<const float4*>(outv) + lflc[pt * 8 + k] * 24 + sub * 6;
#pragma unroll
      for (int i = 0; i < 6; ++i) {
        float4 o = op[i];
        a[i].x += w * o.x; a[i].y += w * o.y; a[i].z += w * o.z; a[i].w += w * o.w;
      }
    }
  }
  if (MODE >= 1) {
#pragma unroll
    for (int i = 0; i < 6; ++i) {
      a[i].x = tanhf(a[i].x); a[i].y = tanhf(a[i].y);
      a[i].z = tanhf(a[i].z); a[i].w = tanhf(a[i].w);
    }
  }
  if (p < n) {
    float4* d4 = reinterpret_cast<float4*>(dst) + p * 24 + sub * 6;
#pragma unroll
    for (int i = 0; i < 6; ++i) d4[i] = a[i];
  }
  if (MODE == 1) {
    const float4* vw4 = reinterpret_cast<const float4*>(vlw + sub * 24);
    float partial = 0.f;
#pragma unroll
    for (int i = 0; i < 6; ++i) {
      float4 vw = vw4[i];
      partial += a[i].x * vw.x + a[i].y * vw.y + a[i].z * vw.z + a[i].w * vw.w;
    }
    partial += __shfl_xor(partial, 1);
    partial += __shfl_xor(partial, 2);
    if (sub == 0 && p < n) attn_out[p] = partial;
  }
}

__global__ void k_attn_final(const float* __restrict__ outvV, const float* __restrict__ vlb,
                             const float* __restrict__ coords, const unsigned* __restrict__ cnt,
                             float* __restrict__ attn, int n) {
  int p = blockIdx.x * 256 + threadIdx.x;
  if (p >= n) return;
  float a = attn[p] + vlb[0];
#pragma unroll
  for (int k = 0; k < 8; ++k) {
    int f; float w;
    corner_one(coords, cnt, p, k, f, w);
    a += w * outvV[f];
  }
  attn[p] = a;
}

// ---------------- launch ----------------

extern "C" void kernel_launch(void* const* d_in, const int* in_sizes, int n_in,
                              void* d_out, int out_size, void* d_ws, size_t ws_size,
                              hipStream_t stream) {
  const float* hidden   = (const float*)d_in[0];
  const float* query    = (const float*)d_in[1];
  const float* coords   = (const float*)d_in[2];
  const float* wq_conv  = (const float*)d_in[3];
  const float* wq_lw    = (const float*)d_in[4];
  const float* wq_lb    = (const float*)d_in[5];
  const float* wh_conv  = (const float*)d_in[6];
  const float* wh_lw    = (const float*)d_in[7];
  const float* wh_lb    = (const float*)d_in[8];
  const float* att_conv = (const float*)d_in[9];
  const float* att_lw   = (const float*)d_in[10];
  const float* att_lb   = (const float*)d_in[11];
  const float* v_conv   = (const float*)d_in[12];
  const float* v_lw     = (const float*)d_in[13];
  const float* v_lb     = (const float*)d_in[14];
  const float* upd_conv = (const float*)d_in[15];
  const float* upd_lw   = (const float*)d_in[16];
  const float* upd_lb   = (const float*)d_in[17];
  float* out = (float*)d_out;
  const int n = in_sizes[0] / CH;

  char* wsp = (char*)d_ws;
  auto alloc = [&](size_t bytes) {
    char* r = wsp;
    wsp += (bytes + 255) & ~(size_t)255;
    return r;
  };
  int*      flat  = (int*)     alloc((size_t)n * 4);
  int*      order = (int*)     alloc((size_t)n * 4);
  unsigned* cnt   = (unsigned*)alloc((size_t)NV * 4);
  unsigned* base  = (unsigned*)alloc((size_t)NV * 4);
  unsigned* cur   = (unsigned*)alloc((size_t)NV * 4);
  float*    inv   = (float*)   alloc((size_t)NV * 4);
  float*    attn  = (float*)   alloc((size_t)n * 4);
  float*    wtv   = (float*)   alloc((size_t)27 * 96 * 4);
  _Float16* wpq = (_Float16*)alloc((size_t)27 * 3 * 6 * 512 * 2);
  _Float16* wph = (_Float16*)alloc((size_t)27 * 3 * 6 * 512 * 2);
  _Float16* wpa = (_Float16*)alloc((size_t)27 * 6 * 6 * 512 * 2);
  _Float16* wpu = (_Float16*)alloc((size_t)27 * 6 * 6 * 512 * 2);
  _Float16* wlq = (_Float16*)alloc((size_t)3 * 6 * 512 * 2);
  _Float16* wlh = (_Float16*)alloc((size_t)3 * 6 * 512 * 2);
  _Float16* wla = (_Float16*)alloc((size_t)6 * 6 * 512 * 2);
  _Float16* wlu = (_Float16*)alloc((size_t)6 * 6 * 512 * 2);
  _Float16* Hin = (_Float16*)alloc((size_t)NV * CH * 2);
  _Float16* H1  = (_Float16*)alloc((size_t)NV * CH * 2);
  _Float16* H2  = (_Float16*)alloc((size_t)NV * CH * 2);
  float* GE   = (float*)alloc((size_t)NV * CH * 4);
  float* O1   = (float*)alloc((size_t)NV * CH * 4);
  float* Ov   = (float*)alloc((size_t)NV * 4);
  float* qv   = (float*)alloc((size_t)n * CH * 4);
  float* hv   = (float*)alloc((size_t)n * CH * 4);
  float* ebuf = (float*)alloc((size_t)n * CH * 4);

  const int nb  = (n + 255) / 256;
  const int npt = (n + 63) / 64;
  const int nva = NV * 24 / 256;   // 3072

  // prep: CSR + weight packs
  hipMemsetAsync(cnt, 0, (size_t)NV * 4, stream);
  k_prep<<<nb, 256, 0, stream>>>(coords, flat, cnt, n);
  k_scan<<<1, 1024, 0, stream>>>(cnt, base, cur, inv);
  k_fill<<<nb, 256, 0, stream>>>(flat, cur, order, n);
  k_tconv<<<(27*96 + 255)/256, 256, 0, stream>>>(v_conv, wtv, 1, 96);
  k_wpack<<<(27*3*6*512 + 255)/256, 256, 0, stream>>>(wq_conv, wpq, 3);
  k_wpack<<<(27*3*6*512 + 255)/256, 256, 0, stream>>>(wh_conv, wph, 3);
  k_wpack<<<(27*6*6*512 + 255)/256, 256, 0, stream>>>(att_conv, wpa, 6);
  k_wpack<<<(27*6*6*512 + 255)/256, 256, 0, stream>>>(upd_conv, wpu, 6);
  k_linpack<<<(3*6*512 + 255)/256, 256, 0, stream>>>(wq_lw, wlq, 3);
  k_linpack<<<(3*6*512 + 255)/256, 256, 0, stream>>>(wh_lw, wlh, 3);
  k_linpack<<<(6*6*512 + 255)/256, 256, 0, stream>>>(att_lw, wla, 6);
  k_linpack<<<(6*6*512 + 255)/256, 256, 0, stream>>>(upd_lw, wlu, 6);

  // stage 1: q = sconv(query)
  k_voxavg<1,0><<<nva, 256, 0, stream>>>((const float4*)query, nullptr, base, cnt, inv, order, Hin);
  k_conv_mfma<3><<<512, 256, 0, stream>>>(Hin, Hin, (const half8*)wpq, O1);
  k_point<3,0><<<npt, 256, 0, stream>>>(O1, query, nullptr, nullptr, (const half8*)wlq,
                                        wq_lb, nullptr, coords, cnt, qv, nullptr, n);

  // stage 2: h = sconv(hidden)
  k_voxavg<1,0><<<nva, 256, 0, stream>>>((const float4*)hidden, nullptr, base, cnt, inv, order, Hin);
  k_conv_mfma<3><<<512, 256, 0, stream>>>(Hin, Hin, (const half8*)wph, O1);
  k_point<3,0><<<npt, 256, 0, stream>>>(O1, hidden, nullptr, nullptr, (const half8*)wlh,
                                        wh_lb, nullptr, coords, cnt, hv, nullptr, n);

  // stage 3: energy = tanh(sconv([h,q])) -> ebuf + v-linear partial (attn)
  k_voxavg<1,0><<<nva, 256, 0, stream>>>((const float4*)hv, nullptr, base, cnt, inv, order, H1);
  k_voxavg<1,0><<<nva, 256, 0, stream>>>((const float4*)qv, nullptr, base, cnt, inv, order, H2);
  k_conv_mfma<6><<<512, 256, 0, stream>>>(H1, H2, (const half8*)wpa, O1);
  k_point<6,1><<<npt, 256, 0, stream>>>(O1, hv, qv, nullptr, (const half8*)wla,
                                        att_lb, v_lw, coords, cnt, ebuf, attn, n);

  // stage 4: attn = sconv(energy) with Cout=1 (fp32 path)
  k_voxavg<0,0><<<nva, 256, 0, stream>>>((const float4*)ebuf, nullptr, base, cnt, inv, order, GE);
  k_conv3d_v<<<1024, 128, 0, stream>>>(GE, wtv, Ov);
  k_attn_final<<<nb, 256, 0, stream>>>(Ov, v_lb, coords, cnt, attn, n);

  // stage 5: out = tanh(sconv([q, attn*h]))
  k_voxavg<1,1><<<nva, 256, 0, stream>>>((const float4*)hv, attn, base, cnt, inv, order, H1);
  k_conv_mfma<6><<<512, 256, 0, stream>>>(H2, H1, (const half8*)wpu, O1);
  k_point<6,2><<<npt, 256, 0, stream>>>(O1, qv, hv, attn, (const half8*)wlu,
                                        upd_lb, nullptr, coords, cnt, out, nullptr, n);
}

// Round 5
// 773.305 us; speedup vs baseline: 8.1260x; 1.1014x over previous
//
#include <hip/hip_runtime.h>
#include <math.h>

// AttenSeq2Seq on a sparse voxel grid. G=32, N=100000, C=96.
// R4: conv_mfma at 512 thr/block (8 waves: col2 x mtile2 x cohalf2) -> 16
// waves/CU latency hiding with unchanged L2 weight traffic; independent
// stage-1/2 dispatches merged (voxavg/conv/point pairs); all weight packing
// in one kernel; energy grid in f16 for the v-conv.
// MFMA layouts (verified): A[m=lane&15][k=(lane>>4)*8+j],
// B[k=(lane>>4)*8+j][n=lane&15], D[row=(lane>>4)*4+reg][col=lane&15].

#define GD 32
#define NV (GD*GD*GD)   // 32768 voxels
#define CH 96

typedef _Float16 half8 __attribute__((ext_vector_type(8)));
typedef float f32x4 __attribute__((ext_vector_type(4)));

// ---------------- prep / CSR ----------------

__global__ void k_prep(const float* __restrict__ coords, int* __restrict__ flat,
                       unsigned* __restrict__ cnt, int n) {
  int i = blockIdx.x * 256 + threadIdx.x;
  if (i >= n) return;
  float x = coords[3*i], y = coords[3*i+1], z = coords[3*i+2];
  int ix = (int)floorf(x); ix = ix < 0 ? 0 : (ix > 31 ? 31 : ix);
  int iy = (int)floorf(y); iy = iy < 0 ? 0 : (iy > 31 ? 31 : iy);
  int iz = (int)floorf(z); iz = iz < 0 ? 0 : (iz > 31 ? 31 : iz);
  int f = (ix << 10) + (iy << 5) + iz;
  flat[i] = f;
  atomicAdd(&cnt[f], 1u);
}

// single-block exclusive scan of cnt[NV] -> base, cur; also inv = 1/cnt.
__global__ __launch_bounds__(1024) void k_scan(
    const unsigned* __restrict__ cnt, unsigned* __restrict__ base,
    unsigned* __restrict__ cur, float* __restrict__ inv) {
  __shared__ unsigned part[1024];
  int tid = threadIdx.x;
  int b0 = tid * 32;
  unsigned s = 0;
  for (int i = 0; i < 32; ++i) s += cnt[b0 + i];
  part[tid] = s;
  __syncthreads();
  for (int off = 1; off < 1024; off <<= 1) {
    unsigned t = (tid >= off) ? part[tid - off] : 0u;
    __syncthreads();
    if (tid >= off) part[tid] += t;
    __syncthreads();
  }
  unsigned run = part[tid] - s;   // exclusive base of this chunk
  for (int i = 0; i < 32; ++i) {
    int v = b0 + i;
    unsigned c = cnt[v];
    base[v] = run; cur[v] = run;
    inv[v] = c ? 1.0f / (float)c : 0.0f;
    run += c;
  }
}

__global__ void k_fill(const int* __restrict__ flat, unsigned* __restrict__ cur,
                       int* __restrict__ order, int n) {
  int p = blockIdx.x * 256 + threadIdx.x;
  if (p >= n) return;
  unsigned pos = atomicAdd(&cur[flat[p]], 1u);
  order[pos] = p;
}

// voxel-gather mean -> f16 grid. Thread = (voxel, float4-chunk of 24).
// PAIR: second half of grid handles (src2 -> dst2).
template<int SCALED, int PAIR>
__global__ void k_voxavg(const float4* __restrict__ src, const float* __restrict__ scale,
                         const unsigned* __restrict__ base, const unsigned* __restrict__ cnt,
                         const float* __restrict__ inv, const int* __restrict__ order,
                         void* __restrict__ dst,
                         const float4* __restrict__ src2, void* __restrict__ dst2) {
  int e = blockIdx.x * 256 + threadIdx.x;   // e < NV*24 (or 2x for PAIR)
  const float4* s4 = src; void* d = dst;
  if (PAIR && e >= NV * 24) { e -= NV * 24; s4 = src2; d = dst2; }
  int v = e / 24, c4 = e - v * 24;
  unsigned b = base[v], c = cnt[v];
  float4 s = {0.f, 0.f, 0.f, 0.f};
  for (unsigned i = 0; i < c; ++i) {
    int p = order[b + i];
    float4 x = s4[p * 24 + c4];
    if (SCALED) {
      float sc = scale[p];
      x.x *= sc; x.y *= sc; x.z *= sc; x.w *= sc;
    }
    s.x += x.x; s.y += x.y; s.z += x.z; s.w += x.w;
  }
  float iv = inv[v];
  s.x *= iv; s.y *= iv; s.z *= iv; s.w *= iv;
  union { _Float16 h; unsigned short u; } h0, h1, h2, h3;
  h0.h = (_Float16)s.x; h1.h = (_Float16)s.y; h2.h = (_Float16)s.z; h3.h = (_Float16)s.w;
  ushort4 o; o.x = h0.u; o.y = h1.u; o.z = h2.u; o.w = h3.u;
  reinterpret_cast<ushort4*>(d)[e] = o;
}

// ---------------- merged weight packing ----------------

__device__ __forceinline__ void wpack_one(int e, const float* __restrict__ w,
                                          _Float16* __restrict__ wp, int nch) {
  int j = e & 7; int l = (e >> 3) & 63; int r = e >> 9;
  int cot = r % 6; r /= 6; int chk = r % nch; int tap = r / nch;
  int Ci = nch * 32;
  int ci = chk * 32 + (l >> 4) * 8 + j;
  int co = cot * 16 + (l & 15);
  wp[e] = (_Float16)w[(co * Ci + ci) * 27 + tap];
}

__device__ __forceinline__ void linpack_one(int e, const float* __restrict__ w,
                                            _Float16* __restrict__ wl, int kb) {
  int j = e & 7; int l = (e >> 3) & 63; int r = e >> 9;
  int nt = r % 6; int kt = r / 6;
  int Ci = kb * 32;
  int ci = kt * 32 + (l >> 4) * 8 + j;
  int co = nt * 16 + (l & 15);
  wl[e] = (_Float16)w[co * Ci + ci];
}

#define WP3 (27*3*6*512)
#define WP6 (27*6*6*512)
#define WL3 (3*6*512)
#define WL6 (6*6*512)
#define PACK_TOTAL (2*WP3 + 2*WP6 + 2*WL3 + 2*WL6 + 27*96)

__global__ void k_packall(
    const float* __restrict__ wq, const float* __restrict__ wh,
    const float* __restrict__ wa, const float* __restrict__ wu,
    const float* __restrict__ lq, const float* __restrict__ lh,
    const float* __restrict__ la, const float* __restrict__ lu,
    const float* __restrict__ wvc,
    _Float16* __restrict__ wpq, _Float16* __restrict__ wph,
    _Float16* __restrict__ wpa, _Float16* __restrict__ wpu,
    _Float16* __restrict__ wlq, _Float16* __restrict__ wlh,
    _Float16* __restrict__ wla, _Float16* __restrict__ wlu,
    float* __restrict__ wtv) {
  int e = blockIdx.x * 256 + threadIdx.x;
  if (e < WP3) { wpack_one(e, wq, wpq, 3); return; } e -= WP3;
  if (e < WP3) { wpack_one(e, wh, wph, 3); return; } e -= WP3;
  if (e < WP6) { wpack_one(e, wa, wpa, 6); return; } e -= WP6;
  if (e < WP6) { wpack_one(e, wu, wpu, 6); return; } e -= WP6;
  if (e < WL3) { linpack_one(e, lq, wlq, 3); return; } e -= WL3;
  if (e < WL3) { linpack_one(e, lh, wlh, 3); return; } e -= WL3;
  if (e < WL6) { linpack_one(e, la, wla, 6); return; } e -= WL6;
  if (e < WL6) { linpack_one(e, lu, wlu, 6); return; } e -= WL6;
  if (e < 27 * 96) {
    int ci = e % 96, tap = e / 96;
    wtv[e] = wvc[ci * 27 + tap];   // (1,96,27) -> (27,96)
  }
}

// ---------------- MFMA 3x3x3 conv ----------------
// 512 threads, 8 waves = (column wcol) x (m-tile mt) x (co-half coh).
// Block = 2 z-columns (x, y0), (x, y0+1). LDS halo 12 cols x 34 z x 32 ci f16
// (rows padded to 40) = 32640 B -> 2 blocks/CU, 16 waves/CU.
// PAIR: blocks [512, 1024) run the second (gA2, wp2, out2) problem.
template<int NCH, int PAIR>   // NCH: 3 (Cin=96) or 6 (Cin=192, 2nd 96 from gB)
__global__ __launch_bounds__(512, 4) void k_conv_mfma(
    const _Float16* __restrict__ gA, const _Float16* __restrict__ gB,
    const half8* __restrict__ wp, float* __restrict__ out,
    const _Float16* __restrict__ gA2, const half8* __restrict__ wp2,
    float* __restrict__ out2) {
  __shared__ unsigned short ls[12 * 34 * 40];
  int bid = blockIdx.x;
  const _Float16* ga = gA; const _Float16* gb = gB;
  const half8* w = wp; float* o = out;
  if (PAIR && bid >= 512) { bid -= 512; ga = gA2; gb = gA2; w = wp2; o = out2; }
  int bx = bid >> 4, y0 = (bid & 15) * 2;
  int tid = threadIdx.x;
  int lane = tid & 63, wv = tid >> 6;
  int wcol = wv & 1, mt = (wv >> 1) & 1, coh = wv >> 2;
  int lrow = lane & 15, quad = lane >> 4;

  f32x4 acc[3];
#pragma unroll
  for (int b = 0; b < 3; ++b) acc[b] = (f32x4){0.f, 0.f, 0.f, 0.f};

  for (int chunk = 0; chunk < NCH; ++chunk) {
    const _Float16* g = (NCH == 6 && chunk >= 3) ? gb : ga;
    int cbase = ((NCH == 6 && chunk >= 3) ? chunk - 3 : chunk) * 32;
    __syncthreads();
    for (int e = tid; e < 12 * 34 * 4; e += 512) {
      int ciu = e & 3; int zc = e >> 2;
      int zz = zc % 34; int sc = zc / 34;
      int dx = sc >> 2, dyy = sc & 3;
      int x = bx + dx - 1, y = y0 + dyy - 1, zv = zz - 1;
      uint4 val = {0u, 0u, 0u, 0u};
      if ((unsigned)x < 32u && (unsigned)y < 32u && (unsigned)zv < 32u)
        val = *reinterpret_cast<const uint4*>(
            g + (size_t)((x << 10) + (y << 5) + zv) * CH + cbase + ciu * 8);
      *reinterpret_cast<uint4*>(&ls[(sc * 34 + zz) * 40 + ciu * 8]) = val;
    }
    __syncthreads();
#pragma unroll
    for (int dx9 = 0; dx9 < 3; ++dx9)
#pragma unroll
      for (int dy9 = 0; dy9 < 3; ++dy9) {
        int sc = dx9 * 4 + wcol + dy9;
        const unsigned short* lbase = &ls[(sc * 34 + mt * 16) * 40 + quad * 8];
        int tap0 = (dx9 * 3 + dy9) * 3;
#pragma unroll
        for (int dz = 0; dz < 3; ++dz) {
          half8 a = *reinterpret_cast<const half8*>(&lbase[(lrow + dz) * 40]);
          const half8* wb = w + ((size_t)((tap0 + dz) * NCH + chunk) * 6 + coh * 3) * 64 + lane;
          half8 b0 = wb[0];
          half8 b1 = wb[64];
          half8 b2 = wb[128];
          acc[0] = __builtin_amdgcn_mfma_f32_16x16x32_f16(a, b0, acc[0], 0, 0, 0);
          acc[1] = __builtin_amdgcn_mfma_f32_16x16x32_f16(a, b1, acc[1], 0, 0, 0);
          acc[2] = __builtin_amdgcn_mfma_f32_16x16x32_f16(a, b2, acc[2], 0, 0, 0);
        }
      }
  }
  int y = y0 + wcol;
  int vb = (bx << 10) + (y << 5);
#pragma unroll
  for (int nt = 0; nt < 3; ++nt)
#pragma unroll
    for (int r = 0; r < 4; ++r) {
      int z = mt * 16 + quad * 4 + r;
      o[(size_t)(vb + z) * CH + coh * 48 + nt * 16 + lrow] = acc[nt][r];
    }
}

// Cout=1 conv (the 'v' attention head): f16 grid in, fp32 math.
__global__ __launch_bounds__(128) void k_conv3d_v(
    const _Float16* __restrict__ g, const float* __restrict__ wt, float* __restrict__ out) {
  __shared__ float lg[9 * 34 * 33];
  __shared__ float red[128];
  int bx = blockIdx.x >> 5, by = blockIdx.x & 31;
  int tid = threadIdx.x;
  int z = tid & 31, part = tid >> 5;
  float acc = 0.f;
  for (int chunk = 0; chunk < 3; ++chunk) {
    int c0 = chunk * 32;
    __syncthreads();
    for (int e = tid; e < 9 * 34 * 32; e += 128) {
      int col = e / 1088; int rem = e - col * 1088;
      int zz = rem >> 5; int c = rem & 31;
      int x = bx + col / 3 - 1;
      int y = by + (col - (col / 3) * 3) - 1;
      int zv = zz - 1;
      float val = 0.f;
      if ((unsigned)x < 32u && (unsigned)y < 32u && (unsigned)zv < 32u)
        val = (float)g[((x << 10) + (y << 5) + zv) * CH + c0 + c];
      lg[(col * 34 + zz) * 33 + c] = val;
    }
    __syncthreads();
    for (int tap = 0; tap < 27; ++tap) {
      int cc = tap / 3, dz = tap - cc * 3;
      const float* lgp = &lg[(cc * 34 + z + dz) * 33 + part * 8];
      const float* wp = wt + tap * CH + c0 + part * 8;
#pragma unroll
      for (int c = 0; c < 8; ++c) acc += lgp[c] * wp[c];
    }
  }
  red[tid] = acc;
  __syncthreads();
  if (part == 0)
    out[(bx << 10) + (by << 5) + z] = red[z] + red[z + 32] + red[z + 64] + red[z + 96];
}

// ---------------- fused point kernel: MFMA linear + trilinear devox ----------------

__device__ __forceinline__ void corner_one(
    const float* __restrict__ coords, const unsigned* __restrict__ cnt,
    int p, int k, int& flc, float& w) {
  float cx = coords[3*p], cy = coords[3*p+1], cz = coords[3*p+2];
  float bx = floorf(cx), by = floorf(cy), bz = floorf(cz);
  float fx = cx - bx, fy = cy - by, fz = cz - bz;
  int dx = (k >> 2) & 1, dy = (k >> 1) & 1, dzz = k & 1;
  int ix = (int)bx + dx, iy = (int)by + dy, iz = (int)bz + dzz;
  bool valid = ((unsigned)ix < 32u) && ((unsigned)iy < 32u) && ((unsigned)iz < 32u);
  int xc = min(max(ix, 0), 31), yc = min(max(iy, 0), 31), zc = min(max(iz, 0), 31);
  flc = (xc << 10) + (yc << 5) + zc;
  float wx = dx ? fx : 1.f - fx;
  float wy = dy ? fy : 1.f - fy;
  float wz = dzz ? fz : 1.f - fz;
  w = (valid && cnt[flc] > 0u) ? wx * wy * wz : 0.f;
}

// KB: 3 (K=96) or 6 (K=192, X = [X1, X2]).
// MODE: 0 = plain (dst = devox+lin+b), 1 = energy (tanh, + attn partial = e.vlw),
//       2 = final (tanh; X2 scaled by `scale` during staging).
// PAIR (MODE 0 only): blocks [npt, 2npt) run (outv2, X1b, wl2, lb2 -> dst2).
template<int KB, int MODE, int PAIR>
__global__ __launch_bounds__(256) void k_point(
    const float* __restrict__ outv, const float* __restrict__ X1, const float* __restrict__ X2,
    const float* __restrict__ scale, const half8* __restrict__ wl,
    const float* __restrict__ lb, const float* __restrict__ vlw,
    const float* __restrict__ coords, const unsigned* __restrict__ cnt,
    float* __restrict__ dst, float* __restrict__ attn_out, int n,
    const float* __restrict__ outv2, const float* __restrict__ X1b,
    const half8* __restrict__ wl2, const float* __restrict__ lb2,
    float* __restrict__ dst2) {
  __shared__ char us[64 * 100 * 4];   // union: f16 A-stage [64][KB*32+8] / fp32 acc [64][100]
  __shared__ int lflc[512];
  __shared__ float lcw[512];
  constexpr int APITCH = KB * 32 + 8;
  int tid = threadIdx.x;
  int bid = blockIdx.x;
  const float* ov = outv; const float* x1 = X1;
  const half8* w = wl; const float* b = lb; float* d = dst;
  if (PAIR) {
    int npt = (n + 63) >> 6;
    if (bid >= npt) { bid -= npt; ov = outv2; x1 = X1b; w = wl2; b = lb2; d = dst2; }
  }
  int p0 = bid * 64;

  // corner table
  for (int e = tid; e < 512; e += 256) {
    int j = e >> 3, k = e & 7, p = p0 + j;
    int f = 0; float wgt = 0.f;
    if (p < n) corner_one(coords, cnt, p, k, f, wgt);
    lflc[e] = f; lcw[e] = wgt;
  }

  // stage A (f16) into LDS
  unsigned short* lsa = reinterpret_cast<unsigned short*>(us);
  constexpr int T4 = 64 * KB * 8;
  for (int e = tid; e < T4; e += 256) {
    int j = e / (KB * 8);
    int q4 = e - j * (KB * 8);
    int p = p0 + j;
    float4 v = {0.f, 0.f, 0.f, 0.f};
    if (p < n) {
      if (KB == 3 || q4 < 24) {
        v = reinterpret_cast<const float4*>(x1)[p * 24 + q4];
      } else {
        v = reinterpret_cast<const float4*>(X2)[p * 24 + (q4 - 24)];
        if (MODE == 2) {
          float sc = scale[p];
          v.x *= sc; v.y *= sc; v.z *= sc; v.w *= sc;
        }
      }
    }
    union { _Float16 h; unsigned short u; } h0, h1, h2, h3;
    h0.h = (_Float16)v.x; h1.h = (_Float16)v.y; h2.h = (_Float16)v.z; h3.h = (_Float16)v.w;
    ushort4 o; o.x = h0.u; o.y = h1.u; o.z = h2.u; o.w = h3.u;
    *reinterpret_cast<ushort4*>(&lsa[j * APITCH + q4 * 4]) = o;
  }
  __syncthreads();

  // MFMA: wave wv handles points [wv*16, wv*16+16), full N=96.
  int lane = tid & 63, wv = tid >> 6;
  int lrow = lane & 15, quad = lane >> 4;
  f32x4 acc[6];
#pragma unroll
  for (int i = 0; i < 6; ++i) acc[i] = (f32x4){0.f, 0.f, 0.f, 0.f};
#pragma unroll
  for (int kt = 0; kt < KB; ++kt) {
    half8 a = *reinterpret_cast<const half8*>(&lsa[(wv * 16 + lrow) * APITCH + kt * 32 + quad * 8]);
    const half8* wb = w + (size_t)(kt * 6) * 64 + lane;
#pragma unroll
    for (int nt = 0; nt < 6; ++nt)
      acc[nt] = __builtin_amdgcn_mfma_f32_16x16x32_f16(a, wb[(size_t)nt * 64], acc[nt], 0, 0, 0);
  }
  __syncthreads();   // done reading lsa; reuse as fp32 acc
  float* lacc = reinterpret_cast<float*>(us);
#pragma unroll
  for (int nt = 0; nt < 6; ++nt)
#pragma unroll
    for (int r = 0; r < 4; ++r)
      lacc[(wv * 16 + quad * 4 + r) * 100 + nt * 16 + lrow] = acc[nt][r];
  __syncthreads();

  // point-major epilogue: 4 threads/point x 24 channels.
  int pt = tid >> 2, sub = tid & 3;
  int p = p0 + pt;
  float4 a[6];
  const float* lrow_p = &lacc[pt * 100 + sub * 24];
#pragma unroll
  for (int i = 0; i < 6; ++i) a[i] = *reinterpret_cast<const float4*>(lrow_p + i * 4);
  const float4* lb4 = reinterpret_cast<const float4*>(b + sub * 24);
#pragma unroll
  for (int i = 0; i < 6; ++i) {
    float4 bb = lb4[i];
    a[i].x += bb.x; a[i].y += bb.y; a[i].z += bb.z; a[i].w += bb.w;
  }
#pragma unroll
  for (int k = 0; k < 8; ++k) {
    float wgt = lcw[pt * 8 + k];
    if (wgt != 0.f) {
      const float4* op = reinterpret_cast<const float4*>(ov) + lflc[pt * 8 + k] * 24 + sub * 6;
#pragma unroll
      for (int i = 0; i < 6; ++i) {
        float4 o = op[i];
        a[i].x += wgt * o.x; a[i].y += wgt * o.y; a[i].z += wgt * o.z; a[i].w += wgt * o.w;
      }
    }
  }
  if (MODE >= 1) {
#pragma unroll
    for (int i = 0; i < 6; ++i) {
      a[i].x = tanhf(a[i].x); a[i].y = tanhf(a[i].y);
      a[i].z = tanhf(a[i].z); a[i].w = tanhf(a[i].w);
    }
  }
  if (p < n) {
    float4* d4 = reinterpret_cast<float4*>(d) + p * 24 + sub * 6;
#pragma unroll
    for (int i = 0; i < 6; ++i) d4[i] = a[i];
  }
  if (MODE == 1) {
    const float4* vw4 = reinterpret_cast<const float4*>(vlw + sub * 24);
    float partial = 0.f;
#pragma unroll
    for (int i = 0; i < 6; ++i) {
      float4 vw = vw4[i];
      partial += a[i].x * vw.x + a[i].y * vw.y + a[i].z * vw.z + a[i].w * vw.w;
    }
    partial += __shfl_xor(partial, 1);
    partial += __shfl_xor(partial, 2);
    if (sub == 0 && p < n) attn_out[p] = partial;
  }
}

__global__ void k_attn_final(const float* __restrict__ outvV, const float* __restrict__ vlb,
                             const float* __restrict__ coords, const unsigned* __restrict__ cnt,
                             float* __restrict__ attn, int n) {
  int p = blockIdx.x * 256 + threadIdx.x;
  if (p >= n) return;
  float a = attn[p] + vlb[0];
#pragma unroll
  for (int k = 0; k < 8; ++k) {
    int f; float w;
    corner_one(coords, cnt, p, k, f, w);
    a += w * outvV[f];
  }
  attn[p] = a;
}

// ---------------- launch ----------------

extern "C" void kernel_launch(void* const* d_in, const int* in_sizes, int n_in,
                              void* d_out, int out_size, void* d_ws, size_t ws_size,
                              hipStream_t stream) {
  const float* hidden   = (const float*)d_in[0];
  const float* query    = (const float*)d_in[1];
  const float* coords   = (const float*)d_in[2];
  const float* wq_conv  = (const float*)d_in[3];
  const float* wq_lw    = (const float*)d_in[4];
  const float* wq_lb    = (const float*)d_in[5];
  const float* wh_conv  = (const float*)d_in[6];
  const float* wh_lw    = (const float*)d_in[7];
  const float* wh_lb    = (const float*)d_in[8];
  const float* att_conv = (const float*)d_in[9];
  const float* att_lw   = (const float*)d_in[10];
  const float* att_lb   = (const float*)d_in[11];
  const float* v_conv   = (const float*)d_in[12];
  const float* v_lw     = (const float*)d_in[13];
  const float* v_lb     = (const float*)d_in[14];
  const float* upd_conv = (const float*)d_in[15];
  const float* upd_lw   = (const float*)d_in[16];
  const float* upd_lb   = (const float*)d_in[17];
  float* out = (float*)d_out;
  const int n = in_sizes[0] / CH;

  char* wsp = (char*)d_ws;
  auto alloc = [&](size_t bytes) {
    char* r = wsp;
    wsp += (bytes + 255) & ~(size_t)255;
    return r;
  };
  int*      flat  = (int*)     alloc((size_t)n * 4);
  int*      order = (int*)     alloc((size_t)n * 4);
  unsigned* cnt   = (unsigned*)alloc((size_t)NV * 4);
  unsigned* base  = (unsigned*)alloc((size_t)NV * 4);
  unsigned* cur   = (unsigned*)alloc((size_t)NV * 4);
  float*    inv   = (float*)   alloc((size_t)NV * 4);
  float*    attn  = (float*)   alloc((size_t)n * 4);
  float*    wtv   = (float*)   alloc((size_t)27 * 96 * 4);
  _Float16* wpq = (_Float16*)alloc((size_t)WP3 * 2);
  _Float16* wph = (_Float16*)alloc((size_t)WP3 * 2);
  _Float16* wpa = (_Float16*)alloc((size_t)WP6 * 2);
  _Float16* wpu = (_Float16*)alloc((size_t)WP6 * 2);
  _Float16* wlq = (_Float16*)alloc((size_t)WL3 * 2);
  _Float16* wlh = (_Float16*)alloc((size_t)WL3 * 2);
  _Float16* wla = (_Float16*)alloc((size_t)WL6 * 2);
  _Float16* wlu = (_Float16*)alloc((size_t)WL6 * 2);
  _Float16* Hq  = (_Float16*)alloc((size_t)NV * CH * 2);
  _Float16* Hh  = (_Float16*)alloc((size_t)NV * CH * 2);
  _Float16* H1  = (_Float16*)alloc((size_t)NV * CH * 2);
  _Float16* H2  = (_Float16*)alloc((size_t)NV * CH * 2);
  float* O1   = (float*)alloc((size_t)NV * CH * 4);
  float* O2   = (float*)alloc((size_t)NV * CH * 4);
  float* Ov   = (float*)alloc((size_t)NV * 4);
  float* qv   = (float*)alloc((size_t)n * CH * 4);
  float* hv   = (float*)alloc((size_t)n * CH * 4);
  float* ebuf = (float*)alloc((size_t)n * CH * 4);

  const int nb  = (n + 255) / 256;
  const int npt = (n + 63) / 64;
  const int nva = NV * 24 / 256;   // 3072

  // prep: CSR + merged weight packing
  hipMemsetAsync(cnt, 0, (size_t)NV * 4, stream);
  k_prep<<<nb, 256, 0, stream>>>(coords, flat, cnt, n);
  k_scan<<<1, 1024, 0, stream>>>(cnt, base, cur, inv);
  k_fill<<<nb, 256, 0, stream>>>(flat, cur, order, n);
  k_packall<<<(PACK_TOTAL + 255) / 256, 256, 0, stream>>>(
      wq_conv, wh_conv, att_conv, upd_conv, wq_lw, wh_lw, att_lw, upd_lw, v_conv,
      wpq, wph, wpa, wpu, wlq, wlh, wla, wlu, wtv);

  // stages 1+2 (merged): q = sconv(query), h = sconv(hidden)
  k_voxavg<0,1><<<2*nva, 256, 0, stream>>>((const float4*)query, nullptr, base, cnt, inv, order,
                                           Hq, (const float4*)hidden, Hh);
  k_conv_mfma<3,1><<<1024, 512, 0, stream>>>(Hq, Hq, (const half8*)wpq, O1,
                                             Hh, (const half8*)wph, O2);
  k_point<3,0,1><<<2*npt, 256, 0, stream>>>(O1, query, nullptr, nullptr, (const half8*)wlq,
                                            wq_lb, nullptr, coords, cnt, qv, nullptr, n,
                                            O2, hidden, (const half8*)wlh, wh_lb, hv);

  // stage 3: energy = tanh(sconv([h,q])) -> ebuf + v-linear partial (attn)
  k_voxavg<0,1><<<2*nva, 256, 0, stream>>>((const float4*)hv, nullptr, base, cnt, inv, order,
                                           H1, (const float4*)qv, H2);
  k_conv_mfma<6,0><<<512, 512, 0, stream>>>(H1, H2, (const half8*)wpa, O1,
                                            nullptr, nullptr, nullptr);
  k_point<6,1,0><<<npt, 256, 0, stream>>>(O1, hv, qv, nullptr, (const half8*)wla,
                                          att_lb, v_lw, coords, cnt, ebuf, attn, n,
                                          nullptr, nullptr, nullptr, nullptr, nullptr);

  // stage 4: attn = sconv(energy) with Cout=1 (f16 grid, fp32 math)
  k_voxavg<0,0><<<nva, 256, 0, stream>>>((const float4*)ebuf, nullptr, base, cnt, inv, order,
                                         Hq, nullptr, nullptr);
  k_conv3d_v<<<1024, 128, 0, stream>>>(Hq, wtv, Ov);
  k_attn_final<<<nb, 256, 0, stream>>>(Ov, v_lb, coords, cnt, attn, n);

  // stage 5: out = tanh(sconv([q, attn*h]))
  k_voxavg<1,0><<<nva, 256, 0, stream>>>((const float4*)hv, attn, base, cnt, inv, order,
                                         H1, nullptr, nullptr);
  k_conv_mfma<6,0><<<512, 512, 0, stream>>>(H2, H1, (const half8*)wpu, O1,
                                            nullptr, nullptr, nullptr);
  k_point<6,2,0><<<npt, 256, 0, stream>>>(O1, qv, hv, attn, (const half8*)wlu,
                                          upd_lb, nullptr, coords, cnt, out, nullptr, n,
                                          nullptr, nullptr, nullptr, nullptr, nullptr);
}